// Round 1
// 856.341 us; speedup vs baseline: 1.1591x; 1.1591x over previous
//
#include <hip/hip_runtime.h>
#include <hip/hip_fp16.h>

#define HIDF 128

typedef float v4f __attribute__((ext_vector_type(4)));
typedef _Float16 half8 __attribute__((ext_vector_type(8)));
typedef float f32x4 __attribute__((ext_vector_type(4)));
struct alignas(8) half4 { __half2 lo, hi; };

static inline int cdiv(int a, int b) { return (a + b - 1) / b; }
static inline size_t alup(size_t b) { return (b + 255) & ~(size_t)255; }

// ---- degree count over dst ----
__global__ void k_deg(const int* __restrict__ dst, int E, int* __restrict__ deg) {
    int i = blockIdx.x * blockDim.x + threadIdx.x;
    if (i < E) atomicAdd(&deg[dst[i]], 1);
}

// ---- dinv = rsqrt(max(deg,1)) ----
__global__ void k_dinv(const int* __restrict__ deg, int N, float* __restrict__ dinv) {
    int i = blockIdx.x * blockDim.x + threadIdx.x;
    if (i < N) {
        float d = (float)deg[i];
        dinv[i] = rsqrtf(fmaxf(d, 1.0f));
    }
}

// ---- coefficients: cL[j]=gamma_L[j]; cH[j]=(-1)^j sum_{k>=j} gamma_H[k]*C(k,j) ----
__global__ void k_coef(const float* __restrict__ gL, const float* __restrict__ gH, int K,
                       float* __restrict__ cL, float* __restrict__ cH) {
    if (threadIdx.x == 0 && blockIdx.x == 0) {
        for (int j = 0; j <= K; ++j) {
            double s = 0.0;
            double C = 1.0;
            for (int k = j; k <= K; ++k) {
                s += (double)gH[k] * C;
                C = C * (double)(k + 1) / (double)(k + 1 - j);
            }
            cH[j] = (j & 1) ? (float)(-s) : (float)s;
            cL[j] = gL[j];
        }
    }
}

// ---- single-block exclusive scan deg -> row_ptr ----
__global__ __launch_bounds__(1024) void k_scan(const int* __restrict__ deg, int N,
                                               int* __restrict__ row_ptr) {
    __shared__ int ls[1024];
    int tid = threadIdx.x;
    int chunk = (N + 1023) / 1024;
    int start = tid * chunk;
    int end = min(start + chunk, N);
    int s = 0;
    for (int i = start; i < end; ++i) s += deg[i];
    ls[tid] = s;
    __syncthreads();
    for (int off = 1; off < 1024; off <<= 1) {
        int v = (tid >= off) ? ls[tid - off] : 0;
        __syncthreads();
        ls[tid] += v;
        __syncthreads();
    }
    int run = ls[tid] - s;
    for (int i = start; i < end; ++i) {
        row_ptr[i] = run;
        run += deg[i];
    }
    if (tid == 1023) row_ptr[N] = run;
}

// ---- scatter edges into CSR (by dst) ----
__global__ void k_scatter(const int* __restrict__ src, const int* __restrict__ dst, int E,
                          const int* __restrict__ row_ptr, int* __restrict__ fill,
                          const float* __restrict__ dinv, int* __restrict__ csr_src,
                          float* __restrict__ csr_w) {
    int i = blockIdx.x * blockDim.x + threadIdx.x;
    if (i < E) {
        int s = src[i], d = dst[i];
        int pos = row_ptr[d] + atomicAdd(&fill[d], 1);
        csr_src[pos] = s;
        csr_w[pos] = dinv[s] * dinv[d];
    }
}

// ---- W_in pre-transpose + fp16 hi/lo split: Wt[n][k], k padded to KP with zeros ----
__global__ __launch_bounds__(512) void k_wprep(const float* __restrict__ W, int Kdim, int KP,
                                               _Float16* __restrict__ Wh,
                                               _Float16* __restrict__ Wl) {
    int i = blockIdx.x * blockDim.x + threadIdx.x;
    int total = 128 * KP;
    if (i >= total) return;
    int n = i / KP;
    int k = i - n * KP;
    float w = (k < Kdim) ? W[(long)k * HIDF + n] : 0.0f;
    _Float16 h = (_Float16)w;
    _Float16 l = (_Float16)(w - (float)h);
    Wh[(long)n * KP + k] = h;
    Wl[(long)n * KP + k] = l;
}

// ================= MFMA input GEMM =================
// Split-precision fp16 MFMA: X = Xh + Xl, W = Wh + Wl (fp16 hi + fp16 residual).
// acc = Xh*Wh + Xl*Wh + Xh*Wl  (fp32 accumulate) -> error ~eps^2 ~= 1e-7, i.e. fp32-grade.
// BM=128 x BN=128 x BK=32; 512 threads = 8 waves in 4x2 grid (32 rows x 64 cols per wave).
// LDS tiles [128][40] fp16: stride 40 halves = 80 B -> per-bank access count is the
// structural minimum for wave64 ds_read_b128 (no conflicts).
// Fragment layouts (m89-verified, gfx950 16x16x32):
//   A: lane holds A[row = lane&15][k = (lane>>4)*8 + j]    (8 contiguous k -> ds_read_b128)
//   B: lane holds B[k = (lane>>4)*8 + j][col = lane&15]    (from n-major Wt -> contiguous)
//   C/D: col = lane&15, row = (lane>>4)*4 + reg
__global__ __launch_bounds__(512) void k_gemm_in_mfma(
    const float* __restrict__ X, const _Float16* __restrict__ Wh,
    const _Float16* __restrict__ Wl, const float* __restrict__ b, __half* __restrict__ U0,
    int M, int Kdim, int KP) {
    __shared__ _Float16 Ah[128][40];
    __shared__ _Float16 Al[128][40];
    __shared__ _Float16 Bh[128][40];
    __shared__ _Float16 Bl[128][40];
    int tid = threadIdx.x;
    int lane = tid & 63;
    int wid = tid >> 6;
    int wr = wid >> 1;   // 0..3: row group of 32
    int wc = wid & 1;    // 0..1: col group of 64
    int lr = lane & 15;
    int kq = lane >> 4;  // 0..3
    int kof = kq * 8;
    int row0 = blockIdx.x * 128;
    int sm = tid >> 2;        // staging row (A) / col n (B), 0..127
    int kk = (tid & 3) * 8;   // staging k offset within tile: 0,8,16,24
    bool k4ok = ((Kdim & 3) == 0);  // float4 alignment guarantee for X rows

    f32x4 acc[2][4] = {};

    for (int k0 = 0; k0 < KP; k0 += 32) {
        // ---- stage B tile (already transposed + split + zero-padded in Wt) ----
        *(half8*)&Bh[sm][kk] = *(const half8*)&Wh[(long)sm * KP + k0 + kk];
        *(half8*)&Bl[sm][kk] = *(const half8*)&Wl[(long)sm * KP + k0 + kk];
        // ---- stage A tile: read fp32 X, split into hi/lo fp16 ----
        {
            int r = row0 + sm;
            int gk = k0 + kk;
            half8 hv, lv;
            if (r < M && (gk + 8) <= Kdim && k4ok) {
                float4 v0 = *(const float4*)&X[(long)r * Kdim + gk];
                float4 v1 = *(const float4*)&X[(long)r * Kdim + gk + 4];
                float xs[8] = {v0.x, v0.y, v0.z, v0.w, v1.x, v1.y, v1.z, v1.w};
#pragma unroll
                for (int j = 0; j < 8; ++j) {
                    _Float16 h = (_Float16)xs[j];
                    hv[j] = h;
                    lv[j] = (_Float16)(xs[j] - (float)h);
                }
            } else {
#pragma unroll
                for (int j = 0; j < 8; ++j) {
                    float x = (r < M && (gk + j) < Kdim) ? X[(long)r * Kdim + gk + j] : 0.0f;
                    _Float16 h = (_Float16)x;
                    hv[j] = h;
                    lv[j] = (_Float16)(x - (float)h);
                }
            }
            *(half8*)&Ah[sm][kk] = hv;
            *(half8*)&Al[sm][kk] = lv;
        }
        __syncthreads();

        half8 a_h0 = *(const half8*)&Ah[wr * 32 + lr][kof];
        half8 a_h1 = *(const half8*)&Ah[wr * 32 + 16 + lr][kof];
        half8 a_l0 = *(const half8*)&Al[wr * 32 + lr][kof];
        half8 a_l1 = *(const half8*)&Al[wr * 32 + 16 + lr][kof];
#pragma unroll
        for (int cg = 0; cg < 4; ++cg) {
            half8 b_h = *(const half8*)&Bh[wc * 64 + cg * 16 + lr][kof];
            half8 b_l = *(const half8*)&Bl[wc * 64 + cg * 16 + lr][kof];
            acc[0][cg] = __builtin_amdgcn_mfma_f32_16x16x32_f16(a_h0, b_h, acc[0][cg], 0, 0, 0);
            acc[1][cg] = __builtin_amdgcn_mfma_f32_16x16x32_f16(a_h1, b_h, acc[1][cg], 0, 0, 0);
            acc[0][cg] = __builtin_amdgcn_mfma_f32_16x16x32_f16(a_l0, b_h, acc[0][cg], 0, 0, 0);
            acc[1][cg] = __builtin_amdgcn_mfma_f32_16x16x32_f16(a_l1, b_h, acc[1][cg], 0, 0, 0);
            acc[0][cg] = __builtin_amdgcn_mfma_f32_16x16x32_f16(a_h0, b_l, acc[0][cg], 0, 0, 0);
            acc[1][cg] = __builtin_amdgcn_mfma_f32_16x16x32_f16(a_h1, b_l, acc[1][cg], 0, 0, 0);
        }
        __syncthreads();
    }

    // ---- epilogue: + bias, convert to fp16 basis vector u0 ----
    float bb[4];
#pragma unroll
    for (int cg = 0; cg < 4; ++cg) bb[cg] = b[wc * 64 + cg * 16 + lr];
#pragma unroll
    for (int i = 0; i < 2; ++i) {
#pragma unroll
        for (int j = 0; j < 4; ++j) {
            int r = row0 + wr * 32 + i * 16 + kq * 4 + j;
            if (r < M) {
#pragma unroll
                for (int cg = 0; cg < 4; ++cg) {
                    int n = wc * 64 + cg * 16 + lr;
                    U0[(long)r * HIDF + n] = __float2half(acc[i][cg][j] + bb[cg]);
                }
            }
        }
    }
}

// ---- fallback: fp32 VALU GEMM + acc init (non-deferred path only) ----
__global__ __launch_bounds__(512) void k_gemm_in_f(
    const float* __restrict__ X, const float* __restrict__ W, const float* __restrict__ b,
    float* __restrict__ H, float* __restrict__ accL, float* __restrict__ accH,
    const float* __restrict__ cL, const float* __restrict__ cH, int M, int Kdim) {
    const int BK = 20;
    __shared__ float As[BK][132];
    __shared__ float Bs[BK][128];
    int tid = threadIdx.x;
    int tx = tid & 31, ty = tid >> 5;
    int row0 = blockIdx.x * 128;
    float acc[8][4] = {};
    for (int k0 = 0; k0 < Kdim; k0 += BK) {
        for (int l = tid; l < 640; l += 512) {
            int m = l / 5, q = l % 5;
            int r = row0 + m;
            float4 v = {0.f, 0.f, 0.f, 0.f};
            if (r < M) v = *(const float4*)&X[(long)r * Kdim + k0 + q * 4];
            As[q * 4 + 0][m] = v.x;
            As[q * 4 + 1][m] = v.y;
            As[q * 4 + 2][m] = v.z;
            As[q * 4 + 3][m] = v.w;
        }
        for (int l = tid; l < 640; l += 512) {
            int k = l >> 5, n = (l & 31) * 4;
            *(float4*)&Bs[k][n] = *(const float4*)&W[(long)(k0 + k) * 128 + n];
        }
        __syncthreads();
#pragma unroll
        for (int k = 0; k < BK; ++k) {
            float4 a0 = *(const float4*)&As[k][ty * 8];
            float4 a1 = *(const float4*)&As[k][ty * 8 + 4];
            float4 bb = *(const float4*)&Bs[k][tx * 4];
            float a[8] = {a0.x, a0.y, a0.z, a0.w, a1.x, a1.y, a1.z, a1.w};
#pragma unroll
            for (int i = 0; i < 8; ++i) {
                acc[i][0] += a[i] * bb.x;
                acc[i][1] += a[i] * bb.y;
                acc[i][2] += a[i] * bb.z;
                acc[i][3] += a[i] * bb.w;
            }
        }
        __syncthreads();
    }
    float g0 = cL[0], h0 = cH[0];
    float4 bias = *(const float4*)&b[tx * 4];
    float bv[4] = {bias.x, bias.y, bias.z, bias.w};
#pragma unroll
    for (int i = 0; i < 8; ++i) {
        int r = row0 + ty * 8 + i;
        if (r < M) {
            long idx = (long)r * 128 + tx * 4;
            float4 vh;
            float* ph = (float*)&vh;
#pragma unroll
            for (int j = 0; j < 4; ++j) ph[j] = acc[i][j] + bv[j];
            *(float4*)&H[idx] = vh;
            float4 vl = {g0 * vh.x, g0 * vh.y, g0 * vh.z, g0 * vh.w};
            float4 vv = {h0 * vh.x, h0 * vh.y, h0 * vh.z, h0 * vh.w};
            *(float4*)&accL[idx] = vl;
            *(float4*)&accH[idx] = vv;
        }
    }
}

// ---- fp16 prop: t_out = P t_in (basis step, no acc) ----
__global__ __launch_bounds__(256) void k_prop_h(
    const int* __restrict__ row_ptr, const int* __restrict__ csr_src,
    const float* __restrict__ csr_w, const __half* __restrict__ t_in,
    __half* __restrict__ t_out, int N) {
    int wave = threadIdx.x >> 6;
    int lane = threadIdx.x & 63;
    int half = lane >> 5;
    int l5 = lane & 31;
    int node = blockIdx.x * 4 + wave;
    if (node >= N) return;
    int e0 = row_ptr[node], e1 = row_ptr[node + 1];
    float sx = 0.f, sy = 0.f, sz = 0.f, sw = 0.f;
    int e = e0 + half;
    for (; e + 6 < e1; e += 8) {
        int i0 = csr_src[e], i1 = csr_src[e + 2], i2 = csr_src[e + 4], i3 = csr_src[e + 6];
        float w0 = csr_w[e], w1 = csr_w[e + 2], w2 = csr_w[e + 4], w3 = csr_w[e + 6];
        half4 v0 = *(const half4*)&t_in[(long)i0 * HIDF + l5 * 4];
        half4 v1 = *(const half4*)&t_in[(long)i1 * HIDF + l5 * 4];
        half4 v2 = *(const half4*)&t_in[(long)i2 * HIDF + l5 * 4];
        half4 v3 = *(const half4*)&t_in[(long)i3 * HIDF + l5 * 4];
        float2 a0 = __half22float2(v0.lo), b0 = __half22float2(v0.hi);
        float2 a1 = __half22float2(v1.lo), b1 = __half22float2(v1.hi);
        float2 a2 = __half22float2(v2.lo), b2 = __half22float2(v2.hi);
        float2 a3 = __half22float2(v3.lo), b3 = __half22float2(v3.hi);
        sx += w0 * a0.x + w1 * a1.x + w2 * a2.x + w3 * a3.x;
        sy += w0 * a0.y + w1 * a1.y + w2 * a2.y + w3 * a3.y;
        sz += w0 * b0.x + w1 * b1.x + w2 * b2.x + w3 * b3.x;
        sw += w0 * b0.y + w1 * b1.y + w2 * b2.y + w3 * b3.y;
    }
    for (; e < e1; e += 2) {
        int i0 = csr_src[e];
        float w0 = csr_w[e];
        half4 v0 = *(const half4*)&t_in[(long)i0 * HIDF + l5 * 4];
        float2 a0 = __half22float2(v0.lo), b0 = __half22float2(v0.hi);
        sx += w0 * a0.x;
        sy += w0 * a0.y;
        sz += w0 * b0.x;
        sw += w0 * b0.y;
    }
    sx += __shfl_xor(sx, 32);
    sy += __shfl_xor(sy, 32);
    sz += __shfl_xor(sz, 32);
    sw += __shfl_xor(sw, 32);
    if (half == 0) {
        half4 o;
        o.lo = __float22half2_rn(make_float2(sx, sy));
        o.hi = __float22half2_rn(make_float2(sz, sw));
        *(half4*)&t_out[(long)node * HIDF + l5 * 4] = o;
    }
}

// ---- fallback fp32 prop ----
__global__ __launch_bounds__(256) void k_prop(
    const int* __restrict__ row_ptr, const int* __restrict__ csr_src,
    const float* __restrict__ csr_w, const float* __restrict__ t_in,
    float* __restrict__ t_out, float* __restrict__ accL, float* __restrict__ accH,
    const float* __restrict__ cL, const float* __restrict__ cH, int j, int N, int write_t) {
    int wave = threadIdx.x >> 6;
    int lane = threadIdx.x & 63;
    int half = lane >> 5;
    int l5 = lane & 31;
    int node = blockIdx.x * 4 + wave;
    if (node >= N) return;
    int e0 = row_ptr[node], e1 = row_ptr[node + 1];
    float sx = 0.f, sy = 0.f, sz = 0.f, sw = 0.f;
    int e = e0 + half;
    for (; e + 6 < e1; e += 8) {
        int i0 = csr_src[e], i1 = csr_src[e + 2], i2 = csr_src[e + 4], i3 = csr_src[e + 6];
        float w0 = csr_w[e], w1 = csr_w[e + 2], w2 = csr_w[e + 4], w3 = csr_w[e + 6];
        float4 v0 = *(const float4*)&t_in[(long)i0 * HIDF + l5 * 4];
        float4 v1 = *(const float4*)&t_in[(long)i1 * HIDF + l5 * 4];
        float4 v2 = *(const float4*)&t_in[(long)i2 * HIDF + l5 * 4];
        float4 v3 = *(const float4*)&t_in[(long)i3 * HIDF + l5 * 4];
        sx += w0 * v0.x + w1 * v1.x + w2 * v2.x + w3 * v3.x;
        sy += w0 * v0.y + w1 * v1.y + w2 * v2.y + w3 * v3.y;
        sz += w0 * v0.z + w1 * v1.z + w2 * v2.z + w3 * v3.z;
        sw += w0 * v0.w + w1 * v1.w + w2 * v2.w + w3 * v3.w;
    }
    for (; e < e1; e += 2) {
        int i0 = csr_src[e];
        float w0 = csr_w[e];
        float4 v0 = *(const float4*)&t_in[(long)i0 * HIDF + l5 * 4];
        sx += w0 * v0.x;
        sy += w0 * v0.y;
        sz += w0 * v0.z;
        sw += w0 * v0.w;
    }
    sx += __shfl_xor(sx, 32);
    sy += __shfl_xor(sy, 32);
    sz += __shfl_xor(sz, 32);
    sw += __shfl_xor(sw, 32);
    if (half == 0) {
        long base = (long)node * HIDF + l5 * 4;
        if (write_t) {
            float4 o = {sx, sy, sz, sw};
            *(float4*)&t_out[base] = o;
        }
        float gL = cL[j], gH = cH[j];
        float4 aL = *(const float4*)&accL[base];
        float4 aH = *(const float4*)&accH[base];
        aL.x += gL * sx; aL.y += gL * sy; aL.z += gL * sz; aL.w += gL * sw;
        aH.x += gH * sx; aH.y += gH * sy; aH.z += gH * sz; aH.w += gH * sw;
        *(float4*)&accL[base] = aL;
        *(float4*)&accH[base] = aH;
    }
}

// ---- fused basis combine + BN stats (fp16 basis) ----
__global__ __launch_bounds__(256) void k_combine_h(
    const __half* __restrict__ tb, long tstride, int K, float* __restrict__ accL,
    float* __restrict__ accH, const float* __restrict__ cL, const float* __restrict__ cH,
    int N, float* __restrict__ sums) {
    int tid = threadIdx.x;
    int l5 = tid & 31;
    int g = tid >> 5;
    float4 s1 = {0, 0, 0, 0}, s2 = {0, 0, 0, 0}, s3 = {0, 0, 0, 0}, s4 = {0, 0, 0, 0};
    for (long r = blockIdx.x * 8 + g; r < N; r += (long)gridDim.x * 8) {
        const __half* p = tb + r * HIDF + l5 * 4;
        float4 aL = {0, 0, 0, 0}, aH = {0, 0, 0, 0};
        for (int j = 0; j <= K; ++j) {
            half4 vh = *(const half4*)(p + (long)j * tstride);
            float2 v01 = __half22float2(vh.lo);
            float2 v23 = __half22float2(vh.hi);
            float gL = cL[j], gH = cH[j];
            aL.x += gL * v01.x; aL.y += gL * v01.y; aL.z += gL * v23.x; aL.w += gL * v23.y;
            aH.x += gH * v01.x; aH.y += gH * v01.y; aH.z += gH * v23.x; aH.w += gH * v23.y;
        }
        long base = r * HIDF + l5 * 4;
        *(float4*)&accL[base] = aL;
        *(float4*)&accH[base] = aH;
        s1.x += aL.x; s1.y += aL.y; s1.z += aL.z; s1.w += aL.w;
        s2.x += aL.x * aL.x; s2.y += aL.y * aL.y; s2.z += aL.z * aL.z; s2.w += aL.w * aL.w;
        s3.x += aH.x; s3.y += aH.y; s3.z += aH.z; s3.w += aH.w;
        s4.x += aH.x * aH.x; s4.y += aH.y * aH.y; s4.z += aH.z * aH.z; s4.w += aH.w * aH.w;
    }
    __shared__ float4 ls1[256], ls2[256], ls3[256], ls4[256];
    ls1[tid] = s1;
    ls2[tid] = s2;
    ls3[tid] = s3;
    ls4[tid] = s4;
    __syncthreads();
    if (tid < 32) {
        float4 a = ls1[tid], bq = ls2[tid], c = ls3[tid], d = ls4[tid];
        for (int gg = 1; gg < 8; ++gg) {
            float4 t;
            t = ls1[gg * 32 + tid]; a.x += t.x; a.y += t.y; a.z += t.z; a.w += t.w;
            t = ls2[gg * 32 + tid]; bq.x += t.x; bq.y += t.y; bq.z += t.z; bq.w += t.w;
            t = ls3[gg * 32 + tid]; c.x += t.x; c.y += t.y; c.z += t.z; c.w += t.w;
            t = ls4[gg * 32 + tid]; d.x += t.x; d.y += t.y; d.z += t.z; d.w += t.w;
        }
        int f = tid * 4;
        atomicAdd(&sums[f + 0], a.x); atomicAdd(&sums[f + 1], a.y);
        atomicAdd(&sums[f + 2], a.z); atomicAdd(&sums[f + 3], a.w);
        atomicAdd(&sums[128 + f + 0], bq.x); atomicAdd(&sums[128 + f + 1], bq.y);
        atomicAdd(&sums[128 + f + 2], bq.z); atomicAdd(&sums[128 + f + 3], bq.w);
        atomicAdd(&sums[256 + f + 0], c.x); atomicAdd(&sums[256 + f + 1], c.y);
        atomicAdd(&sums[256 + f + 2], c.z); atomicAdd(&sums[256 + f + 3], c.w);
        atomicAdd(&sums[384 + f + 0], d.x); atomicAdd(&sums[384 + f + 1], d.y);
        atomicAdd(&sums[384 + f + 2], d.z); atomicAdd(&sums[384 + f + 3], d.w);
    }
}

// ---- standalone BN stats (fallback path) ----
__global__ __launch_bounds__(256) void k_stats(const float* __restrict__ accL,
                                               const float* __restrict__ accH, int N,
                                               float* __restrict__ sums) {
    int tid = threadIdx.x;
    int l5 = tid & 31;
    int g = tid >> 5;
    float4 l1 = {0, 0, 0, 0}, l2 = {0, 0, 0, 0}, h1 = {0, 0, 0, 0}, h2 = {0, 0, 0, 0};
    for (int r = blockIdx.x * 8 + g; r < N; r += gridDim.x * 8) {
        float4 v = *(const float4*)&accL[(long)r * HIDF + l5 * 4];
        l1.x += v.x; l1.y += v.y; l1.z += v.z; l1.w += v.w;
        l2.x += v.x * v.x; l2.y += v.y * v.y; l2.z += v.z * v.z; l2.w += v.w * v.w;
        float4 u = *(const float4*)&accH[(long)r * HIDF + l5 * 4];
        h1.x += u.x; h1.y += u.y; h1.z += u.z; h1.w += u.w;
        h2.x += u.x * u.x; h2.y += u.y * u.y; h2.z += u.z * u.z; h2.w += u.w * u.w;
    }
    __shared__ float4 s1[256], s2[256], s3[256], s4[256];
    s1[tid] = l1; s2[tid] = l2; s3[tid] = h1; s4[tid] = h2;
    __syncthreads();
    if (tid < 32) {
        float4 a = s1[tid], bq = s2[tid], c = s3[tid], d = s4[tid];
        for (int gg = 1; gg < 8; ++gg) {
            float4 t;
            t = s1[gg * 32 + tid]; a.x += t.x; a.y += t.y; a.z += t.z; a.w += t.w;
            t = s2[gg * 32 + tid]; bq.x += t.x; bq.y += t.y; bq.z += t.z; bq.w += t.w;
            t = s3[gg * 32 + tid]; c.x += t.x; c.y += t.y; c.z += t.z; c.w += t.w;
            t = s4[gg * 32 + tid]; d.x += t.x; d.y += t.y; d.z += t.z; d.w += t.w;
        }
        int f = tid * 4;
        atomicAdd(&sums[f + 0], a.x); atomicAdd(&sums[f + 1], a.y);
        atomicAdd(&sums[f + 2], a.z); atomicAdd(&sums[f + 3], a.w);
        atomicAdd(&sums[128 + f + 0], bq.x); atomicAdd(&sums[128 + f + 1], bq.y);
        atomicAdd(&sums[128 + f + 2], bq.z); atomicAdd(&sums[128 + f + 3], bq.w);
        atomicAdd(&sums[256 + f + 0], c.x); atomicAdd(&sums[256 + f + 1], c.y);
        atomicAdd(&sums[256 + f + 2], c.z); atomicAdd(&sums[256 + f + 3], c.w);
        atomicAdd(&sums[384 + f + 0], d.x); atomicAdd(&sums[384 + f + 1], d.y);
        atomicAdd(&sums[384 + f + 2], d.z); atomicAdd(&sums[384 + f + 3], d.w);
    }
}

// ---- finalize BN affine for both encoders ----
__global__ void k_bnfin(const float* __restrict__ sums, int N, const float* __restrict__ scale,
                        const float* __restrict__ shift, float* __restrict__ a_mul,
                        float* __restrict__ a_add) {
    int f = threadIdx.x;
    for (int enc = 0; enc < 2; ++enc) {
        float mu = sums[enc * 256 + f] / (float)N;
        float var = sums[enc * 256 + 128 + f] / (float)N - mu * mu;
        float rstd = rsqrtf(var + 1e-5f);
        float am = rstd * scale[f];
        a_mul[enc * 128 + f] = am;
        a_add[enc * 128 + f] = shift[f] - mu * am;
    }
}

// ---- up GEMM, BN fused at staging, bias+relu; grid.y = encoder ----
__global__ __launch_bounds__(512) void k_gemm_up(
    const float* __restrict__ accL, const float* __restrict__ accH,
    const float* __restrict__ W, const float* __restrict__ bias,
    const float* __restrict__ a_mul, const float* __restrict__ a_add,
    float* __restrict__ out, int M) {
    int enc = blockIdx.y;
    const float* A = enc ? accH : accL;
    float* O = out + (size_t)enc * M * 128;
    __shared__ float As[16][132];
    __shared__ float Bs[16][128];
    __shared__ float ams[128], aas[128];
    int tid = threadIdx.x;
    int tx = tid & 31, ty = tid >> 5;
    int row0 = blockIdx.x * 128;
    if (tid < 128) {
        ams[tid] = a_mul[enc * 128 + tid];
        aas[tid] = a_add[enc * 128 + tid];
    }
    __syncthreads();
    float acc[8][4] = {};
    for (int k0 = 0; k0 < 128; k0 += 16) {
        {
            int m = tid >> 2, q = tid & 3;
            int r = row0 + m;
            float4 v = {0.f, 0.f, 0.f, 0.f};
            if (r < M) v = *(const float4*)&A[(long)r * 128 + k0 + q * 4];
            int kk = q * 4;
            As[kk + 0][m] = v.x * ams[k0 + kk + 0] + aas[k0 + kk + 0];
            As[kk + 1][m] = v.y * ams[k0 + kk + 1] + aas[k0 + kk + 1];
            As[kk + 2][m] = v.z * ams[k0 + kk + 2] + aas[k0 + kk + 2];
            As[kk + 3][m] = v.w * ams[k0 + kk + 3] + aas[k0 + kk + 3];
        }
        {
            int k = tid >> 5, n = (tid & 31) * 4;
            *(float4*)&Bs[k][n] = *(const float4*)&W[(long)(k0 + k) * 128 + n];
        }
        __syncthreads();
#pragma unroll
        for (int k = 0; k < 16; ++k) {
            float4 a0 = *(const float4*)&As[k][ty * 8];
            float4 a1 = *(const float4*)&As[k][ty * 8 + 4];
            float4 bb = *(const float4*)&Bs[k][tx * 4];
            float a[8] = {a0.x, a0.y, a0.z, a0.w, a1.x, a1.y, a1.z, a1.w};
#pragma unroll
            for (int i = 0; i < 8; ++i) {
                acc[i][0] += a[i] * bb.x;
                acc[i][1] += a[i] * bb.y;
                acc[i][2] += a[i] * bb.z;
                acc[i][3] += a[i] * bb.w;
            }
        }
        __syncthreads();
    }
    float4 bv = *(const float4*)&bias[tx * 4];
    float bb[4] = {bv.x, bv.y, bv.z, bv.w};
#pragma unroll
    for (int i = 0; i < 8; ++i) {
        int r = row0 + ty * 8 + i;
        if (r < M) {
            float4 o;
            o.x = fmaxf(acc[i][0] + bb[0], 0.0f);
            o.y = fmaxf(acc[i][1] + bb[1], 0.0f);
            o.z = fmaxf(acc[i][2] + bb[2], 0.0f);
            o.w = fmaxf(acc[i][3] + bb[3], 0.0f);
            *(float4*)&O[(long)r * 128 + tx * 4] = o;
        }
    }
}

extern "C" void kernel_launch(void* const* d_in, const int* in_sizes, int n_in, void* d_out,
                              int out_size, void* d_ws, size_t ws_size, hipStream_t stream) {
    const float* x = (const float*)d_in[0];
    const int* edge_index = (const int*)d_in[1];
    const float* W_in = (const float*)d_in[2];
    const float* b_in = (const float*)d_in[3];
    const float* gamma_L = (const float*)d_in[4];
    const float* gamma_H = (const float*)d_in[5];
    const float* bn_scale = (const float*)d_in[6];
    const float* bn_shift = (const float*)d_in[7];
    const float* W_up = (const float*)d_in[8];
    const float* b_up = (const float*)d_in[9];
    float* out = (float*)d_out;

    const int HID = in_sizes[3];       // 128
    const int IN = in_sizes[2] / HID;  // 500
    const int N = in_sizes[0] / IN;    // 50000
    const int E = in_sizes[1] / 2;     // 800000
    const int K = in_sizes[4] - 1;     // 10

    const int* src = edge_index;
    const int* dst = edge_index + E;

    const int KP = (IN + 31) & ~31;    // K padded to MFMA BK multiple (500 -> 512)

    char* base = (char*)d_ws;
    size_t off = 0;
    auto take = [&](size_t bytes) -> char* {
        char* r = base + off;
        off += alup(bytes);
        return r;
    };
    int* deg = (int*)take((size_t)N * 4);
    int* row_ptr = (int*)take((size_t)(N + 1) * 4);
    int* fill = (int*)take((size_t)N * 4);
    float* dinv = (float*)take((size_t)N * 4);
    int* csr_src = (int*)take((size_t)E * 4);
    float* csr_w = (float*)take((size_t)E * 4);
    float* accL = (float*)take((size_t)N * HID * 4);
    float* accH = (float*)take((size_t)N * HID * 4);
    float* sums = (float*)take(512 * 4);
    float* cL = (float*)take(64 * 4);
    float* cH = (float*)take(64 * 4);
    float* a_mul = (float*)take(256 * 4);
    float* a_add = (float*)take(256 * 4);
    _Float16* Wt_h = (_Float16*)take((size_t)HID * KP * 2);
    _Float16* Wt_l = (_Float16*)take((size_t)HID * KP * 2);

    // fp16 basis: K+1 vectors of N*HID halves
    size_t per16 = alup((size_t)N * HID * 2);
    long stride16 = (long)(per16 / 2);  // in halves
    __half* tb16 = (__half*)(base + off);
    bool deferred = (off + (size_t)(K + 1) * per16) <= ws_size && K < 60;
    // fallback: 2 fp32 ping-pong buffers
    size_t per32 = alup((size_t)N * HID * 4);
    long stride32 = (long)(per32 / 4);
    float* fb = (float*)(base + off);
    if (!deferred && off + 2 * per32 > ws_size) deferred = true;  // (shouldn't happen)

    hipMemsetAsync(deg, 0, (size_t)N * 4, stream);
    hipMemsetAsync(fill, 0, (size_t)N * 4, stream);
    hipMemsetAsync(sums, 0, 512 * 4, stream);

    k_coef<<<1, 64, 0, stream>>>(gamma_L, gamma_H, K, cL, cH);
    k_deg<<<cdiv(E, 256), 256, 0, stream>>>(dst, E, deg);
    k_dinv<<<cdiv(N, 256), 256, 0, stream>>>(deg, N, dinv);
    k_scan<<<1, 1024, 0, stream>>>(deg, N, row_ptr);
    k_scatter<<<cdiv(E, 256), 256, 0, stream>>>(src, dst, E, row_ptr, fill, dinv, csr_src,
                                                csr_w);

    if (deferred) {
        k_wprep<<<cdiv(HID * KP, 512), 512, 0, stream>>>(W_in, IN, KP, Wt_h, Wt_l);
        k_gemm_in_mfma<<<cdiv(N, 128), 512, 0, stream>>>(x, Wt_h, Wt_l, b_in, tb16, N, IN, KP);
        for (int j = 1; j <= K; ++j) {
            const __half* tin = tb16 + (long)(j - 1) * stride16;
            __half* tout = tb16 + (long)j * stride16;
            k_prop_h<<<cdiv(N, 4), 256, 0, stream>>>(row_ptr, csr_src, csr_w, tin, tout, N);
        }
        k_combine_h<<<512, 256, 0, stream>>>(tb16, stride16, K, accL, accH, cL, cH, N, sums);
    } else {
        float* h = fb;
        float* ta = fb + stride32;
        k_gemm_in_f<<<cdiv(N, 128), 512, 0, stream>>>(x, W_in, b_in, h, accL, accH, cL, cH,
                                                      N, IN);
        const float* tin = h;
        float* tout = ta;
        for (int j = 1; j <= K; ++j) {
            int write_t = (j < K) ? 1 : 0;
            k_prop<<<cdiv(N, 4), 256, 0, stream>>>(row_ptr, csr_src, csr_w, tin, tout, accL,
                                                   accH, cL, cH, j, N, write_t);
            const float* nt = tout;
            tout = (nt == ta) ? h : ta;
            tin = nt;
        }
        k_stats<<<200, 256, 0, stream>>>(accL, accH, N, sums);
    }

    k_bnfin<<<1, 128, 0, stream>>>(sums, N, bn_scale, bn_shift, a_mul, a_add);
    dim3 gup(cdiv(N, 128), 2);
    k_gemm_up<<<gup, 512, 0, stream>>>(accL, accH, W_up, b_up, a_mul, a_add, out, N);
}

// Round 2
// 756.622 us; speedup vs baseline: 1.3118x; 1.1318x over previous
//
#include <hip/hip_runtime.h>
#include <hip/hip_fp16.h>

#define HIDF 128

typedef float v4f __attribute__((ext_vector_type(4)));
typedef _Float16 half8 __attribute__((ext_vector_type(8)));
typedef float f32x4 __attribute__((ext_vector_type(4)));
struct alignas(8) half4 { __half2 lo, hi; };

static inline int cdiv(int a, int b) { return (a + b - 1) / b; }
static inline size_t alup(size_t b) { return (b + 255) & ~(size_t)255; }

// ---- degree count over dst ----
__global__ void k_deg(const int* __restrict__ dst, int E, int* __restrict__ deg) {
    int i = blockIdx.x * blockDim.x + threadIdx.x;
    if (i < E) atomicAdd(&deg[dst[i]], 1);
}

// ---- dinv = rsqrt(max(deg,1)) ----
__global__ void k_dinv(const int* __restrict__ deg, int N, float* __restrict__ dinv) {
    int i = blockIdx.x * blockDim.x + threadIdx.x;
    if (i < N) {
        float d = (float)deg[i];
        dinv[i] = rsqrtf(fmaxf(d, 1.0f));
    }
}

// ---- coefficients: cL[j]=gamma_L[j]; cH[j]=(-1)^j sum_{k>=j} gamma_H[k]*C(k,j) ----
__global__ void k_coef(const float* __restrict__ gL, const float* __restrict__ gH, int K,
                       float* __restrict__ cL, float* __restrict__ cH) {
    if (threadIdx.x == 0 && blockIdx.x == 0) {
        for (int j = 0; j <= K; ++j) {
            double s = 0.0;
            double C = 1.0;
            for (int k = j; k <= K; ++k) {
                s += (double)gH[k] * C;
                C = C * (double)(k + 1) / (double)(k + 1 - j);
            }
            cH[j] = (j & 1) ? (float)(-s) : (float)s;
            cL[j] = gL[j];
        }
    }
}

// ---- single-block exclusive scan deg -> row_ptr ----
__global__ __launch_bounds__(1024) void k_scan(const int* __restrict__ deg, int N,
                                               int* __restrict__ row_ptr) {
    __shared__ int ls[1024];
    int tid = threadIdx.x;
    int chunk = (N + 1023) / 1024;
    int start = tid * chunk;
    int end = min(start + chunk, N);
    int s = 0;
    for (int i = start; i < end; ++i) s += deg[i];
    ls[tid] = s;
    __syncthreads();
    for (int off = 1; off < 1024; off <<= 1) {
        int v = (tid >= off) ? ls[tid - off] : 0;
        __syncthreads();
        ls[tid] += v;
        __syncthreads();
    }
    int run = ls[tid] - s;
    for (int i = start; i < end; ++i) {
        row_ptr[i] = run;
        run += deg[i];
    }
    if (tid == 1023) row_ptr[N] = run;
}

// ---- scatter edges into CSR (by dst) ----
__global__ void k_scatter(const int* __restrict__ src, const int* __restrict__ dst, int E,
                          const int* __restrict__ row_ptr, int* __restrict__ fill,
                          const float* __restrict__ dinv, int* __restrict__ csr_src,
                          float* __restrict__ csr_w) {
    int i = blockIdx.x * blockDim.x + threadIdx.x;
    if (i < E) {
        int s = src[i], d = dst[i];
        int pos = row_ptr[d] + atomicAdd(&fill[d], 1);
        csr_src[pos] = s;
        csr_w[pos] = dinv[s] * dinv[d];
    }
}

// ---- W pre-transpose + fp16 hi/lo split: Wt[n][k], k padded to KP with zeros ----
__global__ __launch_bounds__(512) void k_wprep(const float* __restrict__ W, int Kdim, int KP,
                                               _Float16* __restrict__ Wh,
                                               _Float16* __restrict__ Wl) {
    int i = blockIdx.x * blockDim.x + threadIdx.x;
    int total = 128 * KP;
    if (i >= total) return;
    int n = i / KP;
    int k = i - n * KP;
    float w = (k < Kdim) ? W[(long)k * HIDF + n] : 0.0f;
    _Float16 h = (_Float16)w;
    _Float16 l = (_Float16)(w - (float)h);
    Wh[(long)n * KP + k] = h;
    Wl[(long)n * KP + k] = l;
}

// ================= MFMA input GEMM =================
// Split-precision fp16 MFMA: X = Xh + Xl, W = Wh + Wl (fp16 hi + fp16 residual).
// acc = Xh*Wh + Xl*Wh + Xh*Wl  (fp32 accumulate) -> error ~eps^2 ~= 1e-7, i.e. fp32-grade.
__global__ __launch_bounds__(512) void k_gemm_in_mfma(
    const float* __restrict__ X, const _Float16* __restrict__ Wh,
    const _Float16* __restrict__ Wl, const float* __restrict__ b, __half* __restrict__ U0,
    int M, int Kdim, int KP) {
    __shared__ _Float16 Ah[128][40];
    __shared__ _Float16 Al[128][40];
    __shared__ _Float16 Bh[128][40];
    __shared__ _Float16 Bl[128][40];
    int tid = threadIdx.x;
    int lane = tid & 63;
    int wid = tid >> 6;
    int wr = wid >> 1;
    int wc = wid & 1;
    int lr = lane & 15;
    int kq = lane >> 4;
    int kof = kq * 8;
    int row0 = blockIdx.x * 128;
    int sm = tid >> 2;
    int kk = (tid & 3) * 8;
    bool k4ok = ((Kdim & 3) == 0);

    f32x4 acc[2][4] = {};

    for (int k0 = 0; k0 < KP; k0 += 32) {
        *(half8*)&Bh[sm][kk] = *(const half8*)&Wh[(long)sm * KP + k0 + kk];
        *(half8*)&Bl[sm][kk] = *(const half8*)&Wl[(long)sm * KP + k0 + kk];
        {
            int r = row0 + sm;
            int gk = k0 + kk;
            half8 hv, lv;
            if (r < M && (gk + 8) <= Kdim && k4ok) {
                float4 v0 = *(const float4*)&X[(long)r * Kdim + gk];
                float4 v1 = *(const float4*)&X[(long)r * Kdim + gk + 4];
                float xs[8] = {v0.x, v0.y, v0.z, v0.w, v1.x, v1.y, v1.z, v1.w};
#pragma unroll
                for (int j = 0; j < 8; ++j) {
                    _Float16 h = (_Float16)xs[j];
                    hv[j] = h;
                    lv[j] = (_Float16)(xs[j] - (float)h);
                }
            } else {
#pragma unroll
                for (int j = 0; j < 8; ++j) {
                    float x = (r < M && (gk + j) < Kdim) ? X[(long)r * Kdim + gk + j] : 0.0f;
                    _Float16 h = (_Float16)x;
                    hv[j] = h;
                    lv[j] = (_Float16)(x - (float)h);
                }
            }
            *(half8*)&Ah[sm][kk] = hv;
            *(half8*)&Al[sm][kk] = lv;
        }
        __syncthreads();

        half8 a_h0 = *(const half8*)&Ah[wr * 32 + lr][kof];
        half8 a_h1 = *(const half8*)&Ah[wr * 32 + 16 + lr][kof];
        half8 a_l0 = *(const half8*)&Al[wr * 32 + lr][kof];
        half8 a_l1 = *(const half8*)&Al[wr * 32 + 16 + lr][kof];
#pragma unroll
        for (int cg = 0; cg < 4; ++cg) {
            half8 b_h = *(const half8*)&Bh[wc * 64 + cg * 16 + lr][kof];
            half8 b_l = *(const half8*)&Bl[wc * 64 + cg * 16 + lr][kof];
            acc[0][cg] = __builtin_amdgcn_mfma_f32_16x16x32_f16(a_h0, b_h, acc[0][cg], 0, 0, 0);
            acc[1][cg] = __builtin_amdgcn_mfma_f32_16x16x32_f16(a_h1, b_h, acc[1][cg], 0, 0, 0);
            acc[0][cg] = __builtin_amdgcn_mfma_f32_16x16x32_f16(a_l0, b_h, acc[0][cg], 0, 0, 0);
            acc[1][cg] = __builtin_amdgcn_mfma_f32_16x16x32_f16(a_l1, b_h, acc[1][cg], 0, 0, 0);
            acc[0][cg] = __builtin_amdgcn_mfma_f32_16x16x32_f16(a_h0, b_l, acc[0][cg], 0, 0, 0);
            acc[1][cg] = __builtin_amdgcn_mfma_f32_16x16x32_f16(a_h1, b_l, acc[1][cg], 0, 0, 0);
        }
        __syncthreads();
    }

    float bb[4];
#pragma unroll
    for (int cg = 0; cg < 4; ++cg) bb[cg] = b[wc * 64 + cg * 16 + lr];
#pragma unroll
    for (int i = 0; i < 2; ++i) {
#pragma unroll
        for (int j = 0; j < 4; ++j) {
            int r = row0 + wr * 32 + i * 16 + kq * 4 + j;
            if (r < M) {
#pragma unroll
                for (int cg = 0; cg < 4; ++cg) {
                    int n = wc * 64 + cg * 16 + lr;
                    U0[(long)r * HIDF + n] = __float2half(acc[i][cg][j] + bb[cg]);
                }
            }
        }
    }
}

// ================= MFMA up GEMM =================
// z = BN(acc) @ Wup + b = (acc .* am) @ Wup + (aa @ Wup) + b; relu epilogue.
// Same split-precision trick; A tile scaled by am at staging; aaW precomputed in k_bnfin.
__global__ __launch_bounds__(512) void k_gemm_up_mfma(
    const float* __restrict__ accL, const float* __restrict__ accH,
    const _Float16* __restrict__ Wh, const _Float16* __restrict__ Wl,
    const float* __restrict__ bias, const float* __restrict__ a_mul,
    const float* __restrict__ aaW, float* __restrict__ out, int M) {
    int enc = blockIdx.y;
    const float* A = enc ? accH : accL;
    float* O = out + (size_t)enc * M * HIDF;
    __shared__ _Float16 Ah[128][40];
    __shared__ _Float16 Al[128][40];
    __shared__ _Float16 Bh[128][40];
    __shared__ _Float16 Bl[128][40];
    __shared__ float ams[128];
    int tid = threadIdx.x;
    int lane = tid & 63;
    int wid = tid >> 6;
    int wr = wid >> 1;
    int wc = wid & 1;
    int lr = lane & 15;
    int kq = lane >> 4;
    int kof = kq * 8;
    int row0 = blockIdx.x * 128;
    int sm = tid >> 2;
    int kk = (tid & 3) * 8;
    if (tid < 128) ams[tid] = a_mul[enc * 128 + tid];
    __syncthreads();

    f32x4 acc[2][4] = {};

    for (int k0 = 0; k0 < 128; k0 += 32) {
        *(half8*)&Bh[sm][kk] = *(const half8*)&Wh[(long)sm * 128 + k0 + kk];
        *(half8*)&Bl[sm][kk] = *(const half8*)&Wl[(long)sm * 128 + k0 + kk];
        {
            int r = row0 + sm;
            half8 hv, lv;
            if (r < M) {
                float4 v0 = *(const float4*)&A[(long)r * 128 + k0 + kk];
                float4 v1 = *(const float4*)&A[(long)r * 128 + k0 + kk + 4];
                float xs[8] = {v0.x, v0.y, v0.z, v0.w, v1.x, v1.y, v1.z, v1.w};
#pragma unroll
                for (int j = 0; j < 8; ++j) {
                    float sv = xs[j] * ams[k0 + kk + j];
                    _Float16 h = (_Float16)sv;
                    hv[j] = h;
                    lv[j] = (_Float16)(sv - (float)h);
                }
            } else {
#pragma unroll
                for (int j = 0; j < 8; ++j) { hv[j] = (_Float16)0.f; lv[j] = (_Float16)0.f; }
            }
            *(half8*)&Ah[sm][kk] = hv;
            *(half8*)&Al[sm][kk] = lv;
        }
        __syncthreads();

        half8 a_h0 = *(const half8*)&Ah[wr * 32 + lr][kof];
        half8 a_h1 = *(const half8*)&Ah[wr * 32 + 16 + lr][kof];
        half8 a_l0 = *(const half8*)&Al[wr * 32 + lr][kof];
        half8 a_l1 = *(const half8*)&Al[wr * 32 + 16 + lr][kof];
#pragma unroll
        for (int cg = 0; cg < 4; ++cg) {
            half8 b_h = *(const half8*)&Bh[wc * 64 + cg * 16 + lr][kof];
            half8 b_l = *(const half8*)&Bl[wc * 64 + cg * 16 + lr][kof];
            acc[0][cg] = __builtin_amdgcn_mfma_f32_16x16x32_f16(a_h0, b_h, acc[0][cg], 0, 0, 0);
            acc[1][cg] = __builtin_amdgcn_mfma_f32_16x16x32_f16(a_h1, b_h, acc[1][cg], 0, 0, 0);
            acc[0][cg] = __builtin_amdgcn_mfma_f32_16x16x32_f16(a_l0, b_h, acc[0][cg], 0, 0, 0);
            acc[1][cg] = __builtin_amdgcn_mfma_f32_16x16x32_f16(a_l1, b_h, acc[1][cg], 0, 0, 0);
            acc[0][cg] = __builtin_amdgcn_mfma_f32_16x16x32_f16(a_h0, b_l, acc[0][cg], 0, 0, 0);
            acc[1][cg] = __builtin_amdgcn_mfma_f32_16x16x32_f16(a_h1, b_l, acc[1][cg], 0, 0, 0);
        }
        __syncthreads();
    }

    float bb[4];
#pragma unroll
    for (int cg = 0; cg < 4; ++cg) {
        int n = wc * 64 + cg * 16 + lr;
        bb[cg] = bias[n] + aaW[enc * 128 + n];
    }
#pragma unroll
    for (int i = 0; i < 2; ++i) {
#pragma unroll
        for (int j = 0; j < 4; ++j) {
            int r = row0 + wr * 32 + i * 16 + kq * 4 + j;
            if (r < M) {
#pragma unroll
                for (int cg = 0; cg < 4; ++cg) {
                    int n = wc * 64 + cg * 16 + lr;
                    O[(long)r * HIDF + n] = fmaxf(acc[i][cg][j] + bb[cg], 0.0f);
                }
            }
        }
    }
}

// ---- fallback: fp32 VALU GEMM + acc init (non-deferred path only) ----
__global__ __launch_bounds__(512) void k_gemm_in_f(
    const float* __restrict__ X, const float* __restrict__ W, const float* __restrict__ b,
    float* __restrict__ H, float* __restrict__ accL, float* __restrict__ accH,
    const float* __restrict__ cL, const float* __restrict__ cH, int M, int Kdim) {
    const int BK = 20;
    __shared__ float As[BK][132];
    __shared__ float Bs[BK][128];
    int tid = threadIdx.x;
    int tx = tid & 31, ty = tid >> 5;
    int row0 = blockIdx.x * 128;
    float acc[8][4] = {};
    for (int k0 = 0; k0 < Kdim; k0 += BK) {
        for (int l = tid; l < 640; l += 512) {
            int m = l / 5, q = l % 5;
            int r = row0 + m;
            float4 v = {0.f, 0.f, 0.f, 0.f};
            if (r < M) v = *(const float4*)&X[(long)r * Kdim + k0 + q * 4];
            As[q * 4 + 0][m] = v.x;
            As[q * 4 + 1][m] = v.y;
            As[q * 4 + 2][m] = v.z;
            As[q * 4 + 3][m] = v.w;
        }
        for (int l = tid; l < 640; l += 512) {
            int k = l >> 5, n = (l & 31) * 4;
            *(float4*)&Bs[k][n] = *(const float4*)&W[(long)(k0 + k) * 128 + n];
        }
        __syncthreads();
#pragma unroll
        for (int k = 0; k < BK; ++k) {
            float4 a0 = *(const float4*)&As[k][ty * 8];
            float4 a1 = *(const float4*)&As[k][ty * 8 + 4];
            float4 bb = *(const float4*)&Bs[k][tx * 4];
            float a[8] = {a0.x, a0.y, a0.z, a0.w, a1.x, a1.y, a1.z, a1.w};
#pragma unroll
            for (int i = 0; i < 8; ++i) {
                acc[i][0] += a[i] * bb.x;
                acc[i][1] += a[i] * bb.y;
                acc[i][2] += a[i] * bb.z;
                acc[i][3] += a[i] * bb.w;
            }
        }
        __syncthreads();
    }
    float g0 = cL[0], h0 = cH[0];
    float4 bias = *(const float4*)&b[tx * 4];
    float bv[4] = {bias.x, bias.y, bias.z, bias.w};
#pragma unroll
    for (int i = 0; i < 8; ++i) {
        int r = row0 + ty * 8 + i;
        if (r < M) {
            long idx = (long)r * 128 + tx * 4;
            float4 vh;
            float* ph = (float*)&vh;
#pragma unroll
            for (int j = 0; j < 4; ++j) ph[j] = acc[i][j] + bv[j];
            *(float4*)&H[idx] = vh;
            float4 vl = {g0 * vh.x, g0 * vh.y, g0 * vh.z, g0 * vh.w};
            float4 vv = {h0 * vh.x, h0 * vh.y, h0 * vh.z, h0 * vh.w};
            *(float4*)&accL[idx] = vl;
            *(float4*)&accH[idx] = vv;
        }
    }
}

// ---- fp16 prop: t_out = P t_in; 8 gathers in flight per half-wave ----
__global__ __launch_bounds__(256) void k_prop_h(
    const int* __restrict__ row_ptr, const int* __restrict__ csr_src,
    const float* __restrict__ csr_w, const __half* __restrict__ t_in,
    __half* __restrict__ t_out, int N) {
    int wave = threadIdx.x >> 6;
    int lane = threadIdx.x & 63;
    int half = lane >> 5;
    int l5 = lane & 31;
    int node = blockIdx.x * 4 + wave;
    if (node >= N) return;
    int e0 = row_ptr[node], e1 = row_ptr[node + 1];
    float sx = 0.f, sy = 0.f, sz = 0.f, sw = 0.f;
    int e = e0 + half;
    // 8 edges per half per iteration (16 slots per wave)
    for (; e + 14 < e1; e += 16) {
        int idx[8];
        float w[8];
        half4 v[8];
#pragma unroll
        for (int q = 0; q < 8; ++q) {
            idx[q] = csr_src[e + 2 * q];
            w[q] = csr_w[e + 2 * q];
        }
#pragma unroll
        for (int q = 0; q < 8; ++q) v[q] = *(const half4*)&t_in[(long)idx[q] * HIDF + l5 * 4];
#pragma unroll
        for (int q = 0; q < 8; ++q) {
            float2 a = __half22float2(v[q].lo), b2 = __half22float2(v[q].hi);
            sx += w[q] * a.x;
            sy += w[q] * a.y;
            sz += w[q] * b2.x;
            sw += w[q] * b2.y;
        }
    }
    for (; e + 6 < e1; e += 8) {
        int idx[4];
        float w[4];
        half4 v[4];
#pragma unroll
        for (int q = 0; q < 4; ++q) {
            idx[q] = csr_src[e + 2 * q];
            w[q] = csr_w[e + 2 * q];
        }
#pragma unroll
        for (int q = 0; q < 4; ++q) v[q] = *(const half4*)&t_in[(long)idx[q] * HIDF + l5 * 4];
#pragma unroll
        for (int q = 0; q < 4; ++q) {
            float2 a = __half22float2(v[q].lo), b2 = __half22float2(v[q].hi);
            sx += w[q] * a.x;
            sy += w[q] * a.y;
            sz += w[q] * b2.x;
            sw += w[q] * b2.y;
        }
    }
    for (; e < e1; e += 2) {
        int i0 = csr_src[e];
        float w0 = csr_w[e];
        half4 v0 = *(const half4*)&t_in[(long)i0 * HIDF + l5 * 4];
        float2 a0 = __half22float2(v0.lo), b0 = __half22float2(v0.hi);
        sx += w0 * a0.x;
        sy += w0 * a0.y;
        sz += w0 * b0.x;
        sw += w0 * b0.y;
    }
    sx += __shfl_xor(sx, 32);
    sy += __shfl_xor(sy, 32);
    sz += __shfl_xor(sz, 32);
    sw += __shfl_xor(sw, 32);
    if (half == 0) {
        half4 o;
        o.lo = __float22half2_rn(make_float2(sx, sy));
        o.hi = __float22half2_rn(make_float2(sz, sw));
        *(half4*)&t_out[(long)node * HIDF + l5 * 4] = o;
    }
}

// ---- fallback fp32 prop ----
__global__ __launch_bounds__(256) void k_prop(
    const int* __restrict__ row_ptr, const int* __restrict__ csr_src,
    const float* __restrict__ csr_w, const float* __restrict__ t_in,
    float* __restrict__ t_out, float* __restrict__ accL, float* __restrict__ accH,
    const float* __restrict__ cL, const float* __restrict__ cH, int j, int N, int write_t) {
    int wave = threadIdx.x >> 6;
    int lane = threadIdx.x & 63;
    int half = lane >> 5;
    int l5 = lane & 31;
    int node = blockIdx.x * 4 + wave;
    if (node >= N) return;
    int e0 = row_ptr[node], e1 = row_ptr[node + 1];
    float sx = 0.f, sy = 0.f, sz = 0.f, sw = 0.f;
    int e = e0 + half;
    for (; e + 6 < e1; e += 8) {
        int i0 = csr_src[e], i1 = csr_src[e + 2], i2 = csr_src[e + 4], i3 = csr_src[e + 6];
        float w0 = csr_w[e], w1 = csr_w[e + 2], w2 = csr_w[e + 4], w3 = csr_w[e + 6];
        float4 v0 = *(const float4*)&t_in[(long)i0 * HIDF + l5 * 4];
        float4 v1 = *(const float4*)&t_in[(long)i1 * HIDF + l5 * 4];
        float4 v2 = *(const float4*)&t_in[(long)i2 * HIDF + l5 * 4];
        float4 v3 = *(const float4*)&t_in[(long)i3 * HIDF + l5 * 4];
        sx += w0 * v0.x + w1 * v1.x + w2 * v2.x + w3 * v3.x;
        sy += w0 * v0.y + w1 * v1.y + w2 * v2.y + w3 * v3.y;
        sz += w0 * v0.z + w1 * v1.z + w2 * v2.z + w3 * v3.z;
        sw += w0 * v0.w + w1 * v1.w + w2 * v2.w + w3 * v3.w;
    }
    for (; e < e1; e += 2) {
        int i0 = csr_src[e];
        float w0 = csr_w[e];
        float4 v0 = *(const float4*)&t_in[(long)i0 * HIDF + l5 * 4];
        sx += w0 * v0.x;
        sy += w0 * v0.y;
        sz += w0 * v0.z;
        sw += w0 * v0.w;
    }
    sx += __shfl_xor(sx, 32);
    sy += __shfl_xor(sy, 32);
    sz += __shfl_xor(sz, 32);
    sw += __shfl_xor(sw, 32);
    if (half == 0) {
        long base = (long)node * HIDF + l5 * 4;
        if (write_t) {
            float4 o = {sx, sy, sz, sw};
            *(float4*)&t_out[base] = o;
        }
        float gL = cL[j], gH = cH[j];
        float4 aL = *(const float4*)&accL[base];
        float4 aH = *(const float4*)&accH[base];
        aL.x += gL * sx; aL.y += gL * sy; aL.z += gL * sz; aL.w += gL * sw;
        aH.x += gH * sx; aH.y += gH * sy; aH.z += gH * sz; aH.w += gH * sw;
        *(float4*)&accL[base] = aL;
        *(float4*)&accH[base] = aH;
    }
}

// ---- fused basis combine + BN stats, v2: all basis loads in flight ----
// 256 threads: fg = tid&15 (8 features), rg = tid>>4 (16 rows per block-iter).
__global__ __launch_bounds__(256) void k_combine_h2(
    const __half* __restrict__ tb, long tstride, int K, float* __restrict__ accL,
    float* __restrict__ accH, const float* __restrict__ cL, const float* __restrict__ cH,
    int N, float* __restrict__ sums) {
    int tid = threadIdx.x;
    int fg = tid & 15;
    int rg = tid >> 4;
    int lane = tid & 63;
    int wid = tid >> 6;
    float s1[8] = {}, s2[8] = {}, s3[8] = {}, s4[8] = {};

    if (K == 10) {
        float gl[11], gh[11];
#pragma unroll
        for (int j = 0; j < 11; ++j) {
            gl[j] = cL[j];
            gh[j] = cH[j];
        }
        for (long r = (long)blockIdx.x * 16 + rg; r < N; r += (long)gridDim.x * 16) {
            const __half* p = tb + r * HIDF + fg * 8;
            half8 v[11];
#pragma unroll
            for (int j = 0; j < 11; ++j) v[j] = *(const half8*)(p + (long)j * tstride);
            float aL[8] = {}, aH[8] = {};
#pragma unroll
            for (int j = 0; j < 11; ++j) {
#pragma unroll
                for (int e = 0; e < 8; ++e) {
                    float t = (float)v[j][e];
                    aL[e] += gl[j] * t;
                    aH[e] += gh[j] * t;
                }
            }
            long base = r * HIDF + fg * 8;
            float4 o0 = {aL[0], aL[1], aL[2], aL[3]};
            float4 o1 = {aL[4], aL[5], aL[6], aL[7]};
            float4 o2 = {aH[0], aH[1], aH[2], aH[3]};
            float4 o3 = {aH[4], aH[5], aH[6], aH[7]};
            *(float4*)&accL[base] = o0;
            *(float4*)&accL[base + 4] = o1;
            *(float4*)&accH[base] = o2;
            *(float4*)&accH[base + 4] = o3;
#pragma unroll
            for (int e = 0; e < 8; ++e) {
                s1[e] += aL[e];
                s2[e] += aL[e] * aL[e];
                s3[e] += aH[e];
                s4[e] += aH[e] * aH[e];
            }
        }
    } else {
        for (long r = (long)blockIdx.x * 16 + rg; r < N; r += (long)gridDim.x * 16) {
            const __half* p = tb + r * HIDF + fg * 8;
            float aL[8] = {}, aH[8] = {};
            for (int j = 0; j <= K; ++j) {
                half8 v = *(const half8*)(p + (long)j * tstride);
                float gL = cL[j], gH = cH[j];
#pragma unroll
                for (int e = 0; e < 8; ++e) {
                    float t = (float)v[e];
                    aL[e] += gL * t;
                    aH[e] += gH * t;
                }
            }
            long base = r * HIDF + fg * 8;
            float4 o0 = {aL[0], aL[1], aL[2], aL[3]};
            float4 o1 = {aL[4], aL[5], aL[6], aL[7]};
            float4 o2 = {aH[0], aH[1], aH[2], aH[3]};
            float4 o3 = {aH[4], aH[5], aH[6], aH[7]};
            *(float4*)&accL[base] = o0;
            *(float4*)&accL[base + 4] = o1;
            *(float4*)&accH[base] = o2;
            *(float4*)&accH[base + 4] = o3;
#pragma unroll
            for (int e = 0; e < 8; ++e) {
                s1[e] += aL[e];
                s2[e] += aL[e] * aL[e];
                s3[e] += aH[e];
                s4[e] += aH[e] * aH[e];
            }
        }
    }

    // reduce over the 4 row-subgroups within each wave (lane>>4)
#pragma unroll
    for (int e = 0; e < 8; ++e) {
        s1[e] += __shfl_xor(s1[e], 16); s1[e] += __shfl_xor(s1[e], 32);
        s2[e] += __shfl_xor(s2[e], 16); s2[e] += __shfl_xor(s2[e], 32);
        s3[e] += __shfl_xor(s3[e], 16); s3[e] += __shfl_xor(s3[e], 32);
        s4[e] += __shfl_xor(s4[e], 16); s4[e] += __shfl_xor(s4[e], 32);
    }
    __shared__ float ls[4][16][32];
    if (lane < 16) {
#pragma unroll
        for (int e = 0; e < 8; ++e) {
            ls[wid][lane][e] = s1[e];
            ls[wid][lane][8 + e] = s2[e];
            ls[wid][lane][16 + e] = s3[e];
            ls[wid][lane][24 + e] = s4[e];
        }
    }
    __syncthreads();
    for (int idx = tid; idx < 512; idx += 256) {
        int f16i = idx >> 5, j = idx & 31;
        float v = ls[0][f16i][j] + ls[1][f16i][j] + ls[2][f16i][j] + ls[3][f16i][j];
        int stat = j >> 3, e = j & 7;
        atomicAdd(&sums[stat * 128 + f16i * 8 + e], v);
    }
}

// ---- standalone BN stats (fallback path) ----
__global__ __launch_bounds__(256) void k_stats(const float* __restrict__ accL,
                                               const float* __restrict__ accH, int N,
                                               float* __restrict__ sums) {
    int tid = threadIdx.x;
    int l5 = tid & 31;
    int g = tid >> 5;
    float4 l1 = {0, 0, 0, 0}, l2 = {0, 0, 0, 0}, h1 = {0, 0, 0, 0}, h2 = {0, 0, 0, 0};
    for (int r = blockIdx.x * 8 + g; r < N; r += gridDim.x * 8) {
        float4 v = *(const float4*)&accL[(long)r * HIDF + l5 * 4];
        l1.x += v.x; l1.y += v.y; l1.z += v.z; l1.w += v.w;
        l2.x += v.x * v.x; l2.y += v.y * v.y; l2.z += v.z * v.z; l2.w += v.w * v.w;
        float4 u = *(const float4*)&accH[(long)r * HIDF + l5 * 4];
        h1.x += u.x; h1.y += u.y; h1.z += u.z; h1.w += u.w;
        h2.x += u.x * u.x; h2.y += u.y * u.y; h2.z += u.z * u.z; h2.w += u.w * u.w;
    }
    __shared__ float4 s1[256], s2[256], s3[256], s4[256];
    s1[tid] = l1; s2[tid] = l2; s3[tid] = h1; s4[tid] = h2;
    __syncthreads();
    if (tid < 32) {
        float4 a = s1[tid], bq = s2[tid], c = s3[tid], d = s4[tid];
        for (int gg = 1; gg < 8; ++gg) {
            float4 t;
            t = s1[gg * 32 + tid]; a.x += t.x; a.y += t.y; a.z += t.z; a.w += t.w;
            t = s2[gg * 32 + tid]; bq.x += t.x; bq.y += t.y; bq.z += t.z; bq.w += t.w;
            t = s3[gg * 32 + tid]; c.x += t.x; c.y += t.y; c.z += t.z; c.w += t.w;
            t = s4[gg * 32 + tid]; d.x += t.x; d.y += t.y; d.z += t.z; d.w += t.w;
        }
        int f = tid * 4;
        atomicAdd(&sums[f + 0], a.x); atomicAdd(&sums[f + 1], a.y);
        atomicAdd(&sums[f + 2], a.z); atomicAdd(&sums[f + 3], a.w);
        atomicAdd(&sums[128 + f + 0], bq.x); atomicAdd(&sums[128 + f + 1], bq.y);
        atomicAdd(&sums[128 + f + 2], bq.z); atomicAdd(&sums[128 + f + 3], bq.w);
        atomicAdd(&sums[256 + f + 0], c.x); atomicAdd(&sums[256 + f + 1], c.y);
        atomicAdd(&sums[256 + f + 2], c.z); atomicAdd(&sums[256 + f + 3], c.w);
        atomicAdd(&sums[384 + f + 0], d.x); atomicAdd(&sums[384 + f + 1], d.y);
        atomicAdd(&sums[384 + f + 2], d.z); atomicAdd(&sums[384 + f + 3], d.w);
    }
}

// ---- finalize BN affine for both encoders + aaW = a_add @ W_up ----
__global__ void k_bnfin(const float* __restrict__ sums, int N, const float* __restrict__ scale,
                        const float* __restrict__ shift, const float* __restrict__ Wup,
                        float* __restrict__ a_mul, float* __restrict__ a_add,
                        float* __restrict__ aaW) {
    __shared__ float sh_add[2][128];
    int f = threadIdx.x;
    for (int enc = 0; enc < 2; ++enc) {
        float mu = sums[enc * 256 + f] / (float)N;
        float var = sums[enc * 256 + 128 + f] / (float)N - mu * mu;
        float rstd = rsqrtf(var + 1e-5f);
        float am = rstd * scale[f];
        a_mul[enc * 128 + f] = am;
        float ad = shift[f] - mu * am;
        a_add[enc * 128 + f] = ad;
        sh_add[enc][f] = ad;
    }
    __syncthreads();
    int n = f;
    float s0 = 0.f, s1 = 0.f;
    for (int ff = 0; ff < 128; ++ff) {
        float w = Wup[ff * 128 + n];
        s0 += sh_add[0][ff] * w;
        s1 += sh_add[1][ff] * w;
    }
    aaW[n] = s0;
    aaW[128 + n] = s1;
}

extern "C" void kernel_launch(void* const* d_in, const int* in_sizes, int n_in, void* d_out,
                              int out_size, void* d_ws, size_t ws_size, hipStream_t stream) {
    const float* x = (const float*)d_in[0];
    const int* edge_index = (const int*)d_in[1];
    const float* W_in = (const float*)d_in[2];
    const float* b_in = (const float*)d_in[3];
    const float* gamma_L = (const float*)d_in[4];
    const float* gamma_H = (const float*)d_in[5];
    const float* bn_scale = (const float*)d_in[6];
    const float* bn_shift = (const float*)d_in[7];
    const float* W_up = (const float*)d_in[8];
    const float* b_up = (const float*)d_in[9];
    float* out = (float*)d_out;

    const int HID = in_sizes[3];       // 128
    const int IN = in_sizes[2] / HID;  // 500
    const int N = in_sizes[0] / IN;    // 50000
    const int E = in_sizes[1] / 2;     // 800000
    const int K = in_sizes[4] - 1;     // 10

    const int* src = edge_index;
    const int* dst = edge_index + E;

    const int KP = (IN + 31) & ~31;    // 500 -> 512

    char* base = (char*)d_ws;
    size_t off = 0;
    auto take = [&](size_t bytes) -> char* {
        char* r = base + off;
        off += alup(bytes);
        return r;
    };
    int* deg = (int*)take((size_t)N * 4);
    int* row_ptr = (int*)take((size_t)(N + 1) * 4);
    int* fill = (int*)take((size_t)N * 4);
    float* dinv = (float*)take((size_t)N * 4);
    int* csr_src = (int*)take((size_t)E * 4);
    float* csr_w = (float*)take((size_t)E * 4);
    float* accL = (float*)take((size_t)N * HID * 4);
    float* accH = (float*)take((size_t)N * HID * 4);
    float* sums = (float*)take(512 * 4);
    float* cL = (float*)take(64 * 4);
    float* cH = (float*)take(64 * 4);
    float* a_mul = (float*)take(256 * 4);
    float* a_add = (float*)take(256 * 4);
    float* aaW = (float*)take(256 * 4);
    _Float16* Wt_h = (_Float16*)take((size_t)HID * KP * 2);
    _Float16* Wt_l = (_Float16*)take((size_t)HID * KP * 2);
    _Float16* Wup_h = (_Float16*)take((size_t)HID * HID * 2);
    _Float16* Wup_l = (_Float16*)take((size_t)HID * HID * 2);

    size_t per16 = alup((size_t)N * HID * 2);
    long stride16 = (long)(per16 / 2);
    __half* tb16 = (__half*)(base + off);
    bool deferred = (off + (size_t)(K + 1) * per16) <= ws_size && K < 60;
    size_t per32 = alup((size_t)N * HID * 4);
    long stride32 = (long)(per32 / 4);
    float* fb = (float*)(base + off);
    if (!deferred && off + 2 * per32 > ws_size) deferred = true;

    hipMemsetAsync(deg, 0, (size_t)N * 4, stream);
    hipMemsetAsync(fill, 0, (size_t)N * 4, stream);
    hipMemsetAsync(sums, 0, 512 * 4, stream);

    k_coef<<<1, 64, 0, stream>>>(gamma_L, gamma_H, K, cL, cH);
    k_deg<<<cdiv(E, 256), 256, 0, stream>>>(dst, E, deg);
    k_dinv<<<cdiv(N, 256), 256, 0, stream>>>(deg, N, dinv);
    k_scan<<<1, 1024, 0, stream>>>(deg, N, row_ptr);
    k_scatter<<<cdiv(E, 256), 256, 0, stream>>>(src, dst, E, row_ptr, fill, dinv, csr_src,
                                                csr_w);
    k_wprep<<<cdiv(HID * HID, 512), 512, 0, stream>>>(W_up, HID, HID, Wup_h, Wup_l);

    if (deferred) {
        k_wprep<<<cdiv(HID * KP, 512), 512, 0, stream>>>(W_in, IN, KP, Wt_h, Wt_l);
        k_gemm_in_mfma<<<cdiv(N, 128), 512, 0, stream>>>(x, Wt_h, Wt_l, b_in, tb16, N, IN, KP);
        for (int j = 1; j <= K; ++j) {
            const __half* tin = tb16 + (long)(j - 1) * stride16;
            __half* tout = tb16 + (long)j * stride16;
            k_prop_h<<<cdiv(N, 4), 256, 0, stream>>>(row_ptr, csr_src, csr_w, tin, tout, N);
        }
        k_combine_h2<<<512, 256, 0, stream>>>(tb16, stride16, K, accL, accH, cL, cH, N, sums);
    } else {
        float* h = fb;
        float* ta = fb + stride32;
        k_gemm_in_f<<<cdiv(N, 128), 512, 0, stream>>>(x, W_in, b_in, h, accL, accH, cL, cH,
                                                      N, IN);
        const float* tin = h;
        float* tout = ta;
        for (int j = 1; j <= K; ++j) {
            int write_t = (j < K) ? 1 : 0;
            k_prop<<<cdiv(N, 4), 256, 0, stream>>>(row_ptr, csr_src, csr_w, tin, tout, accL,
                                                   accH, cL, cH, j, N, write_t);
            const float* nt = tout;
            tout = (nt == ta) ? h : ta;
            tin = nt;
        }
        k_stats<<<200, 256, 0, stream>>>(accL, accH, N, sums);
    }

    k_bnfin<<<1, 128, 0, stream>>>(sums, N, bn_scale, bn_shift, W_up, a_mul, a_add, aaW);
    dim3 gup(cdiv(N, 128), 2);
    k_gemm_up_mfma<<<gup, 512, 0, stream>>>(accL, accH, Wup_h, Wup_l, b_up, a_mul, aaW, out,
                                            N);
}

// Round 3
// 682.679 us; speedup vs baseline: 1.4539x; 1.1083x over previous
//
#include <hip/hip_runtime.h>
#include <hip/hip_fp16.h>

#define HIDF 128

typedef float v4f __attribute__((ext_vector_type(4)));
typedef _Float16 half8 __attribute__((ext_vector_type(8)));
typedef float f32x4 __attribute__((ext_vector_type(4)));
struct alignas(8) half4 { __half2 lo, hi; };

static inline int cdiv(int a, int b) { return (a + b - 1) / b; }
static inline size_t alup(size_t b) { return (b + 255) & ~(size_t)255; }

// ---- degree count over dst ----
__global__ void k_deg(const int* __restrict__ dst, int E, int* __restrict__ deg) {
    int i = blockIdx.x * blockDim.x + threadIdx.x;
    if (i < E) atomicAdd(&deg[dst[i]], 1);
}

// ---- coefficients: cL[j]=gamma_L[j]; cH[j]=(-1)^j sum_{k>=j} gamma_H[k]*C(k,j) ----
__global__ void k_coef(const float* __restrict__ gL, const float* __restrict__ gH, int K,
                       float* __restrict__ cL, float* __restrict__ cH) {
    if (threadIdx.x == 0 && blockIdx.x == 0) {
        for (int j = 0; j <= K; ++j) {
            double s = 0.0;
            double C = 1.0;
            for (int k = j; k <= K; ++k) {
                s += (double)gH[k] * C;
                C = C * (double)(k + 1) / (double)(k + 1 - j);
            }
            cH[j] = (j & 1) ? (float)(-s) : (float)s;
            cL[j] = gL[j];
        }
    }
}

// ---- multi-block scan, phase 1: block sums of deg + dinv fused ----
__global__ __launch_bounds__(256) void k_scan1(const int* __restrict__ deg, int N,
                                               int* __restrict__ bsum,
                                               float* __restrict__ dinv) {
    __shared__ int ls[256];
    int tid = threadIdx.x;
    int i = blockIdx.x * 256 + tid;
    int v = 0;
    if (i < N) {
        v = deg[i];
        dinv[i] = rsqrtf(fmaxf((float)v, 1.0f));
    }
    ls[tid] = v;
    __syncthreads();
    for (int off = 128; off > 0; off >>= 1) {
        if (tid < off) ls[tid] += ls[tid + off];
        __syncthreads();
    }
    if (tid == 0) bsum[blockIdx.x] = ls[0];
}

// ---- phase 2: exclusive scan of block sums (nb <= 1024) ----
__global__ __launch_bounds__(1024) void k_scan2(int* __restrict__ bsum, int nb) {
    __shared__ int ls[1024];
    int tid = threadIdx.x;
    int v = (tid < nb) ? bsum[tid] : 0;
    ls[tid] = v;
    __syncthreads();
    for (int off = 1; off < 1024; off <<= 1) {
        int t = (tid >= off) ? ls[tid - off] : 0;
        __syncthreads();
        ls[tid] += t;
        __syncthreads();
    }
    if (tid < nb) bsum[tid] = ls[tid] - v;
}

// ---- phase 3: per-block exclusive scan + offset -> row_ptr[0..N] ----
__global__ __launch_bounds__(256) void k_scan3(const int* __restrict__ deg,
                                               const int* __restrict__ bsum, int N,
                                               int* __restrict__ row_ptr) {
    __shared__ int ls[256];
    int tid = threadIdx.x;
    int i = blockIdx.x * 256 + tid;
    int v = (i < N) ? deg[i] : 0;
    ls[tid] = v;
    __syncthreads();
    for (int off = 1; off < 256; off <<= 1) {
        int t = (tid >= off) ? ls[tid - off] : 0;
        __syncthreads();
        ls[tid] += t;
        __syncthreads();
    }
    if (i <= N) row_ptr[i] = bsum[blockIdx.x] + ls[tid] - v;
}

// ---- fallback: single-block scan (N > 262143 only) + dinv ----
__global__ __launch_bounds__(1024) void k_scan(const int* __restrict__ deg, int N,
                                               int* __restrict__ row_ptr,
                                               float* __restrict__ dinv) {
    __shared__ int ls[1024];
    int tid = threadIdx.x;
    int chunk = (N + 1023) / 1024;
    int start = tid * chunk;
    int end = min(start + chunk, N);
    int s = 0;
    for (int i = start; i < end; ++i) {
        int d = deg[i];
        s += d;
        dinv[i] = rsqrtf(fmaxf((float)d, 1.0f));
    }
    ls[tid] = s;
    __syncthreads();
    for (int off = 1; off < 1024; off <<= 1) {
        int v = (tid >= off) ? ls[tid - off] : 0;
        __syncthreads();
        ls[tid] += v;
        __syncthreads();
    }
    int run = ls[tid] - s;
    for (int i = start; i < end; ++i) {
        row_ptr[i] = run;
        run += deg[i];
    }
    if (tid == 1023) row_ptr[N] = run;
}

// ---- scatter edges into CSR (by dst) ----
__global__ void k_scatter(const int* __restrict__ src, const int* __restrict__ dst, int E,
                          const int* __restrict__ row_ptr, int* __restrict__ fill,
                          const float* __restrict__ dinv, int* __restrict__ csr_src,
                          float* __restrict__ csr_w) {
    int i = blockIdx.x * blockDim.x + threadIdx.x;
    if (i < E) {
        int s = src[i], d = dst[i];
        int pos = row_ptr[d] + atomicAdd(&fill[d], 1);
        csr_src[pos] = s;
        csr_w[pos] = dinv[s] * dinv[d];
    }
}

// ---- W pre-transpose + fp16 hi/lo split: Wt[n][k], k padded to KP with zeros ----
__global__ __launch_bounds__(512) void k_wprep(const float* __restrict__ W, int Kdim, int KP,
                                               _Float16* __restrict__ Wh,
                                               _Float16* __restrict__ Wl) {
    int i = blockIdx.x * blockDim.x + threadIdx.x;
    int total = 128 * KP;
    if (i >= total) return;
    int n = i / KP;
    int k = i - n * KP;
    float w = (k < Kdim) ? W[(long)k * HIDF + n] : 0.0f;
    _Float16 h = (_Float16)w;
    _Float16 l = (_Float16)(w - (float)h);
    Wh[(long)n * KP + k] = h;
    Wl[(long)n * KP + k] = l;
}

// ================= MFMA input GEMM =================
// Split-precision fp16 MFMA: X = Xh + Xl, W = Wh + Wl (fp16 hi + fp16 residual).
// acc = Xh*Wh + Xl*Wh + Xh*Wl  (fp32 accumulate) -> error ~eps^2 ~= 1e-7, i.e. fp32-grade.
__global__ __launch_bounds__(512) void k_gemm_in_mfma(
    const float* __restrict__ X, const _Float16* __restrict__ Wh,
    const _Float16* __restrict__ Wl, const float* __restrict__ b, __half* __restrict__ U0,
    int M, int Kdim, int KP) {
    __shared__ _Float16 Ah[128][40];
    __shared__ _Float16 Al[128][40];
    __shared__ _Float16 Bh[128][40];
    __shared__ _Float16 Bl[128][40];
    int tid = threadIdx.x;
    int lane = tid & 63;
    int wid = tid >> 6;
    int wr = wid >> 1;
    int wc = wid & 1;
    int lr = lane & 15;
    int kq = lane >> 4;
    int kof = kq * 8;
    int row0 = blockIdx.x * 128;
    int sm = tid >> 2;
    int kk = (tid & 3) * 8;
    bool k4ok = ((Kdim & 3) == 0);

    f32x4 acc[2][4] = {};

    for (int k0 = 0; k0 < KP; k0 += 32) {
        *(half8*)&Bh[sm][kk] = *(const half8*)&Wh[(long)sm * KP + k0 + kk];
        *(half8*)&Bl[sm][kk] = *(const half8*)&Wl[(long)sm * KP + k0 + kk];
        {
            int r = row0 + sm;
            int gk = k0 + kk;
            half8 hv, lv;
            if (r < M && (gk + 8) <= Kdim && k4ok) {
                float4 v0 = *(const float4*)&X[(long)r * Kdim + gk];
                float4 v1 = *(const float4*)&X[(long)r * Kdim + gk + 4];
                float xs[8] = {v0.x, v0.y, v0.z, v0.w, v1.x, v1.y, v1.z, v1.w};
#pragma unroll
                for (int j = 0; j < 8; ++j) {
                    _Float16 h = (_Float16)xs[j];
                    hv[j] = h;
                    lv[j] = (_Float16)(xs[j] - (float)h);
                }
            } else {
#pragma unroll
                for (int j = 0; j < 8; ++j) {
                    float x = (r < M && (gk + j) < Kdim) ? X[(long)r * Kdim + gk + j] : 0.0f;
                    _Float16 h = (_Float16)x;
                    hv[j] = h;
                    lv[j] = (_Float16)(x - (float)h);
                }
            }
            *(half8*)&Ah[sm][kk] = hv;
            *(half8*)&Al[sm][kk] = lv;
        }
        __syncthreads();

        half8 a_h0 = *(const half8*)&Ah[wr * 32 + lr][kof];
        half8 a_h1 = *(const half8*)&Ah[wr * 32 + 16 + lr][kof];
        half8 a_l0 = *(const half8*)&Al[wr * 32 + lr][kof];
        half8 a_l1 = *(const half8*)&Al[wr * 32 + 16 + lr][kof];
#pragma unroll
        for (int cg = 0; cg < 4; ++cg) {
            half8 b_h = *(const half8*)&Bh[wc * 64 + cg * 16 + lr][kof];
            half8 b_l = *(const half8*)&Bl[wc * 64 + cg * 16 + lr][kof];
            acc[0][cg] = __builtin_amdgcn_mfma_f32_16x16x32_f16(a_h0, b_h, acc[0][cg], 0, 0, 0);
            acc[1][cg] = __builtin_amdgcn_mfma_f32_16x16x32_f16(a_h1, b_h, acc[1][cg], 0, 0, 0);
            acc[0][cg] = __builtin_amdgcn_mfma_f32_16x16x32_f16(a_l0, b_h, acc[0][cg], 0, 0, 0);
            acc[1][cg] = __builtin_amdgcn_mfma_f32_16x16x32_f16(a_l1, b_h, acc[1][cg], 0, 0, 0);
            acc[0][cg] = __builtin_amdgcn_mfma_f32_16x16x32_f16(a_h0, b_l, acc[0][cg], 0, 0, 0);
            acc[1][cg] = __builtin_amdgcn_mfma_f32_16x16x32_f16(a_h1, b_l, acc[1][cg], 0, 0, 0);
        }
        __syncthreads();
    }

    float bb[4];
#pragma unroll
    for (int cg = 0; cg < 4; ++cg) bb[cg] = b[wc * 64 + cg * 16 + lr];
#pragma unroll
    for (int i = 0; i < 2; ++i) {
#pragma unroll
        for (int j = 0; j < 4; ++j) {
            int r = row0 + wr * 32 + i * 16 + kq * 4 + j;
            if (r < M) {
#pragma unroll
                for (int cg = 0; cg < 4; ++cg) {
                    int n = wc * 64 + cg * 16 + lr;
                    U0[(long)r * HIDF + n] = __float2half(acc[i][cg][j] + bb[cg]);
                }
            }
        }
    }
}

// ================= MFMA up GEMM =================
// z = BN(acc) @ Wup + b = (acc .* am) @ Wup + (aa @ Wup) + b; relu epilogue.
__global__ __launch_bounds__(512) void k_gemm_up_mfma(
    const float* __restrict__ accL, const float* __restrict__ accH,
    const _Float16* __restrict__ Wh, const _Float16* __restrict__ Wl,
    const float* __restrict__ bias, const float* __restrict__ a_mul,
    const float* __restrict__ aaW, float* __restrict__ out, int M) {
    int enc = blockIdx.y;
    const float* A = enc ? accH : accL;
    float* O = out + (size_t)enc * M * HIDF;
    __shared__ _Float16 Ah[128][40];
    __shared__ _Float16 Al[128][40];
    __shared__ _Float16 Bh[128][40];
    __shared__ _Float16 Bl[128][40];
    __shared__ float ams[128];
    int tid = threadIdx.x;
    int lane = tid & 63;
    int wid = tid >> 6;
    int wr = wid >> 1;
    int wc = wid & 1;
    int lr = lane & 15;
    int kq = lane >> 4;
    int kof = kq * 8;
    int row0 = blockIdx.x * 128;
    int sm = tid >> 2;
    int kk = (tid & 3) * 8;
    if (tid < 128) ams[tid] = a_mul[enc * 128 + tid];
    __syncthreads();

    f32x4 acc[2][4] = {};

    for (int k0 = 0; k0 < 128; k0 += 32) {
        *(half8*)&Bh[sm][kk] = *(const half8*)&Wh[(long)sm * 128 + k0 + kk];
        *(half8*)&Bl[sm][kk] = *(const half8*)&Wl[(long)sm * 128 + k0 + kk];
        {
            int r = row0 + sm;
            half8 hv, lv;
            if (r < M) {
                float4 v0 = *(const float4*)&A[(long)r * 128 + k0 + kk];
                float4 v1 = *(const float4*)&A[(long)r * 128 + k0 + kk + 4];
                float xs[8] = {v0.x, v0.y, v0.z, v0.w, v1.x, v1.y, v1.z, v1.w};
#pragma unroll
                for (int j = 0; j < 8; ++j) {
                    float sv = xs[j] * ams[k0 + kk + j];
                    _Float16 h = (_Float16)sv;
                    hv[j] = h;
                    lv[j] = (_Float16)(sv - (float)h);
                }
            } else {
#pragma unroll
                for (int j = 0; j < 8; ++j) { hv[j] = (_Float16)0.f; lv[j] = (_Float16)0.f; }
            }
            *(half8*)&Ah[sm][kk] = hv;
            *(half8*)&Al[sm][kk] = lv;
        }
        __syncthreads();

        half8 a_h0 = *(const half8*)&Ah[wr * 32 + lr][kof];
        half8 a_h1 = *(const half8*)&Ah[wr * 32 + 16 + lr][kof];
        half8 a_l0 = *(const half8*)&Al[wr * 32 + lr][kof];
        half8 a_l1 = *(const half8*)&Al[wr * 32 + 16 + lr][kof];
#pragma unroll
        for (int cg = 0; cg < 4; ++cg) {
            half8 b_h = *(const half8*)&Bh[wc * 64 + cg * 16 + lr][kof];
            half8 b_l = *(const half8*)&Bl[wc * 64 + cg * 16 + lr][kof];
            acc[0][cg] = __builtin_amdgcn_mfma_f32_16x16x32_f16(a_h0, b_h, acc[0][cg], 0, 0, 0);
            acc[1][cg] = __builtin_amdgcn_mfma_f32_16x16x32_f16(a_h1, b_h, acc[1][cg], 0, 0, 0);
            acc[0][cg] = __builtin_amdgcn_mfma_f32_16x16x32_f16(a_l0, b_h, acc[0][cg], 0, 0, 0);
            acc[1][cg] = __builtin_amdgcn_mfma_f32_16x16x32_f16(a_l1, b_h, acc[1][cg], 0, 0, 0);
            acc[0][cg] = __builtin_amdgcn_mfma_f32_16x16x32_f16(a_h0, b_l, acc[0][cg], 0, 0, 0);
            acc[1][cg] = __builtin_amdgcn_mfma_f32_16x16x32_f16(a_h1, b_l, acc[1][cg], 0, 0, 0);
        }
        __syncthreads();
    }

    float bb[4];
#pragma unroll
    for (int cg = 0; cg < 4; ++cg) {
        int n = wc * 64 + cg * 16 + lr;
        bb[cg] = bias[n] + aaW[enc * 128 + n];
    }
#pragma unroll
    for (int i = 0; i < 2; ++i) {
#pragma unroll
        for (int j = 0; j < 4; ++j) {
            int r = row0 + wr * 32 + i * 16 + kq * 4 + j;
            if (r < M) {
#pragma unroll
                for (int cg = 0; cg < 4; ++cg) {
                    int n = wc * 64 + cg * 16 + lr;
                    O[(long)r * HIDF + n] = fmaxf(acc[i][cg][j] + bb[cg], 0.0f);
                }
            }
        }
    }
}

// ---- fallback: fp32 VALU GEMM + acc init (non-deferred path only) ----
__global__ __launch_bounds__(512) void k_gemm_in_f(
    const float* __restrict__ X, const float* __restrict__ W, const float* __restrict__ b,
    float* __restrict__ H, float* __restrict__ accL, float* __restrict__ accH,
    const float* __restrict__ cL, const float* __restrict__ cH, int M, int Kdim) {
    const int BK = 20;
    __shared__ float As[BK][132];
    __shared__ float Bs[BK][128];
    int tid = threadIdx.x;
    int tx = tid & 31, ty = tid >> 5;
    int row0 = blockIdx.x * 128;
    float acc[8][4] = {};
    for (int k0 = 0; k0 < Kdim; k0 += BK) {
        for (int l = tid; l < 640; l += 512) {
            int m = l / 5, q = l % 5;
            int r = row0 + m;
            float4 v = {0.f, 0.f, 0.f, 0.f};
            if (r < M) v = *(const float4*)&X[(long)r * Kdim + k0 + q * 4];
            As[q * 4 + 0][m] = v.x;
            As[q * 4 + 1][m] = v.y;
            As[q * 4 + 2][m] = v.z;
            As[q * 4 + 3][m] = v.w;
        }
        for (int l = tid; l < 640; l += 512) {
            int k = l >> 5, n = (l & 31) * 4;
            *(float4*)&Bs[k][n] = *(const float4*)&W[(long)(k0 + k) * 128 + n];
        }
        __syncthreads();
#pragma unroll
        for (int k = 0; k < BK; ++k) {
            float4 a0 = *(const float4*)&As[k][ty * 8];
            float4 a1 = *(const float4*)&As[k][ty * 8 + 4];
            float4 bb = *(const float4*)&Bs[k][tx * 4];
            float a[8] = {a0.x, a0.y, a0.z, a0.w, a1.x, a1.y, a1.z, a1.w};
#pragma unroll
            for (int i = 0; i < 8; ++i) {
                acc[i][0] += a[i] * bb.x;
                acc[i][1] += a[i] * bb.y;
                acc[i][2] += a[i] * bb.z;
                acc[i][3] += a[i] * bb.w;
            }
        }
        __syncthreads();
    }
    float g0 = cL[0], h0 = cH[0];
    float4 bias = *(const float4*)&b[tx * 4];
    float bv[4] = {bias.x, bias.y, bias.z, bias.w};
#pragma unroll
    for (int i = 0; i < 8; ++i) {
        int r = row0 + ty * 8 + i;
        if (r < M) {
            long idx = (long)r * 128 + tx * 4;
            float4 vh;
            float* ph = (float*)&vh;
#pragma unroll
            for (int j = 0; j < 4; ++j) ph[j] = acc[i][j] + bv[j];
            *(float4*)&H[idx] = vh;
            float4 vl = {g0 * vh.x, g0 * vh.y, g0 * vh.z, g0 * vh.w};
            float4 vv = {h0 * vh.x, h0 * vh.y, h0 * vh.z, h0 * vh.w};
            *(float4*)&accL[idx] = vl;
            *(float4*)&accH[idx] = vv;
        }
    }
}

// ---- fp16 prop: t_out = P t_in; 8 gathers in flight per half-wave ----
__global__ __launch_bounds__(256) void k_prop_h(
    const int* __restrict__ row_ptr, const int* __restrict__ csr_src,
    const float* __restrict__ csr_w, const __half* __restrict__ t_in,
    __half* __restrict__ t_out, int N) {
    int wave = threadIdx.x >> 6;
    int lane = threadIdx.x & 63;
    int half = lane >> 5;
    int l5 = lane & 31;
    int node = blockIdx.x * 4 + wave;
    if (node >= N) return;
    int e0 = row_ptr[node], e1 = row_ptr[node + 1];
    float sx = 0.f, sy = 0.f, sz = 0.f, sw = 0.f;
    int e = e0 + half;
    for (; e + 14 < e1; e += 16) {
        int idx[8];
        float w[8];
        half4 v[8];
#pragma unroll
        for (int q = 0; q < 8; ++q) {
            idx[q] = csr_src[e + 2 * q];
            w[q] = csr_w[e + 2 * q];
        }
#pragma unroll
        for (int q = 0; q < 8; ++q) v[q] = *(const half4*)&t_in[(long)idx[q] * HIDF + l5 * 4];
#pragma unroll
        for (int q = 0; q < 8; ++q) {
            float2 a = __half22float2(v[q].lo), b2 = __half22float2(v[q].hi);
            sx += w[q] * a.x;
            sy += w[q] * a.y;
            sz += w[q] * b2.x;
            sw += w[q] * b2.y;
        }
    }
    for (; e + 6 < e1; e += 8) {
        int idx[4];
        float w[4];
        half4 v[4];
#pragma unroll
        for (int q = 0; q < 4; ++q) {
            idx[q] = csr_src[e + 2 * q];
            w[q] = csr_w[e + 2 * q];
        }
#pragma unroll
        for (int q = 0; q < 4; ++q) v[q] = *(const half4*)&t_in[(long)idx[q] * HIDF + l5 * 4];
#pragma unroll
        for (int q = 0; q < 4; ++q) {
            float2 a = __half22float2(v[q].lo), b2 = __half22float2(v[q].hi);
            sx += w[q] * a.x;
            sy += w[q] * a.y;
            sz += w[q] * b2.x;
            sw += w[q] * b2.y;
        }
    }
    for (; e < e1; e += 2) {
        int i0 = csr_src[e];
        float w0 = csr_w[e];
        half4 v0 = *(const half4*)&t_in[(long)i0 * HIDF + l5 * 4];
        float2 a0 = __half22float2(v0.lo), b0 = __half22float2(v0.hi);
        sx += w0 * a0.x;
        sy += w0 * a0.y;
        sz += w0 * b0.x;
        sw += w0 * b0.y;
    }
    sx += __shfl_xor(sx, 32);
    sy += __shfl_xor(sy, 32);
    sz += __shfl_xor(sz, 32);
    sw += __shfl_xor(sw, 32);
    if (half == 0) {
        half4 o;
        o.lo = __float22half2_rn(make_float2(sx, sy));
        o.hi = __float22half2_rn(make_float2(sz, sw));
        *(half4*)&t_out[(long)node * HIDF + l5 * 4] = o;
    }
}

// ---- fallback fp32 prop ----
__global__ __launch_bounds__(256) void k_prop(
    const int* __restrict__ row_ptr, const int* __restrict__ csr_src,
    const float* __restrict__ csr_w, const float* __restrict__ t_in,
    float* __restrict__ t_out, float* __restrict__ accL, float* __restrict__ accH,
    const float* __restrict__ cL, const float* __restrict__ cH, int j, int N, int write_t) {
    int wave = threadIdx.x >> 6;
    int lane = threadIdx.x & 63;
    int half = lane >> 5;
    int l5 = lane & 31;
    int node = blockIdx.x * 4 + wave;
    if (node >= N) return;
    int e0 = row_ptr[node], e1 = row_ptr[node + 1];
    float sx = 0.f, sy = 0.f, sz = 0.f, sw = 0.f;
    int e = e0 + half;
    for (; e + 6 < e1; e += 8) {
        int i0 = csr_src[e], i1 = csr_src[e + 2], i2 = csr_src[e + 4], i3 = csr_src[e + 6];
        float w0 = csr_w[e], w1 = csr_w[e + 2], w2 = csr_w[e + 4], w3 = csr_w[e + 6];
        float4 v0 = *(const float4*)&t_in[(long)i0 * HIDF + l5 * 4];
        float4 v1 = *(const float4*)&t_in[(long)i1 * HIDF + l5 * 4];
        float4 v2 = *(const float4*)&t_in[(long)i2 * HIDF + l5 * 4];
        float4 v3 = *(const float4*)&t_in[(long)i3 * HIDF + l5 * 4];
        sx += w0 * v0.x + w1 * v1.x + w2 * v2.x + w3 * v3.x;
        sy += w0 * v0.y + w1 * v1.y + w2 * v2.y + w3 * v3.y;
        sz += w0 * v0.z + w1 * v1.z + w2 * v2.z + w3 * v3.z;
        sw += w0 * v0.w + w1 * v1.w + w2 * v2.w + w3 * v3.w;
    }
    for (; e < e1; e += 2) {
        int i0 = csr_src[e];
        float w0 = csr_w[e];
        float4 v0 = *(const float4*)&t_in[(long)i0 * HIDF + l5 * 4];
        sx += w0 * v0.x;
        sy += w0 * v0.y;
        sz += w0 * v0.z;
        sw += w0 * v0.w;
    }
    sx += __shfl_xor(sx, 32);
    sy += __shfl_xor(sy, 32);
    sz += __shfl_xor(sz, 32);
    sw += __shfl_xor(sw, 32);
    if (half == 0) {
        long base = (long)node * HIDF + l5 * 4;
        if (write_t) {
            float4 o = {sx, sy, sz, sw};
            *(float4*)&t_out[base] = o;
        }
        float gL = cL[j], gH = cH[j];
        float4 aL = *(const float4*)&accL[base];
        float4 aH = *(const float4*)&accH[base];
        aL.x += gL * sx; aL.y += gL * sy; aL.z += gL * sz; aL.w += gL * sw;
        aH.x += gH * sx; aH.y += gH * sy; aH.z += gH * sz; aH.w += gH * sw;
        *(float4*)&accL[base] = aL;
        *(float4*)&accH[base] = aH;
    }
}

// ---- fused basis combine + BN stats, v2: all basis loads in flight ----
__global__ __launch_bounds__(256) void k_combine_h2(
    const __half* __restrict__ tb, long tstride, int K, float* __restrict__ accL,
    float* __restrict__ accH, const float* __restrict__ cL, const float* __restrict__ cH,
    int N, float* __restrict__ sums) {
    int tid = threadIdx.x;
    int fg = tid & 15;
    int rg = tid >> 4;
    int lane = tid & 63;
    int wid = tid >> 6;
    float s1[8] = {}, s2[8] = {}, s3[8] = {}, s4[8] = {};

    if (K == 10) {
        float gl[11], gh[11];
#pragma unroll
        for (int j = 0; j < 11; ++j) {
            gl[j] = cL[j];
            gh[j] = cH[j];
        }
        for (long r = (long)blockIdx.x * 16 + rg; r < N; r += (long)gridDim.x * 16) {
            const __half* p = tb + r * HIDF + fg * 8;
            half8 v[11];
#pragma unroll
            for (int j = 0; j < 11; ++j) v[j] = *(const half8*)(p + (long)j * tstride);
            float aL[8] = {}, aH[8] = {};
#pragma unroll
            for (int j = 0; j < 11; ++j) {
#pragma unroll
                for (int e = 0; e < 8; ++e) {
                    float t = (float)v[j][e];
                    aL[e] += gl[j] * t;
                    aH[e] += gh[j] * t;
                }
            }
            long base = r * HIDF + fg * 8;
            float4 o0 = {aL[0], aL[1], aL[2], aL[3]};
            float4 o1 = {aL[4], aL[5], aL[6], aL[7]};
            float4 o2 = {aH[0], aH[1], aH[2], aH[3]};
            float4 o3 = {aH[4], aH[5], aH[6], aH[7]};
            *(float4*)&accL[base] = o0;
            *(float4*)&accL[base + 4] = o1;
            *(float4*)&accH[base] = o2;
            *(float4*)&accH[base + 4] = o3;
#pragma unroll
            for (int e = 0; e < 8; ++e) {
                s1[e] += aL[e];
                s2[e] += aL[e] * aL[e];
                s3[e] += aH[e];
                s4[e] += aH[e] * aH[e];
            }
        }
    } else {
        for (long r = (long)blockIdx.x * 16 + rg; r < N; r += (long)gridDim.x * 16) {
            const __half* p = tb + r * HIDF + fg * 8;
            float aL[8] = {}, aH[8] = {};
            for (int j = 0; j <= K; ++j) {
                half8 v = *(const half8*)(p + (long)j * tstride);
                float gL = cL[j], gH = cH[j];
#pragma unroll
                for (int e = 0; e < 8; ++e) {
                    float t = (float)v[e];
                    aL[e] += gL * t;
                    aH[e] += gH * t;
                }
            }
            long base = r * HIDF + fg * 8;
            float4 o0 = {aL[0], aL[1], aL[2], aL[3]};
            float4 o1 = {aL[4], aL[5], aL[6], aL[7]};
            float4 o2 = {aH[0], aH[1], aH[2], aH[3]};
            float4 o3 = {aH[4], aH[5], aH[6], aH[7]};
            *(float4*)&accL[base] = o0;
            *(float4*)&accL[base + 4] = o1;
            *(float4*)&accH[base] = o2;
            *(float4*)&accH[base + 4] = o3;
#pragma unroll
            for (int e = 0; e < 8; ++e) {
                s1[e] += aL[e];
                s2[e] += aL[e] * aL[e];
                s3[e] += aH[e];
                s4[e] += aH[e] * aH[e];
            }
        }
    }

#pragma unroll
    for (int e = 0; e < 8; ++e) {
        s1[e] += __shfl_xor(s1[e], 16); s1[e] += __shfl_xor(s1[e], 32);
        s2[e] += __shfl_xor(s2[e], 16); s2[e] += __shfl_xor(s2[e], 32);
        s3[e] += __shfl_xor(s3[e], 16); s3[e] += __shfl_xor(s3[e], 32);
        s4[e] += __shfl_xor(s4[e], 16); s4[e] += __shfl_xor(s4[e], 32);
    }
    __shared__ float ls[4][16][32];
    if (lane < 16) {
#pragma unroll
        for (int e = 0; e < 8; ++e) {
            ls[wid][lane][e] = s1[e];
            ls[wid][lane][8 + e] = s2[e];
            ls[wid][lane][16 + e] = s3[e];
            ls[wid][lane][24 + e] = s4[e];
        }
    }
    __syncthreads();
    for (int idx = tid; idx < 512; idx += 256) {
        int f16i = idx >> 5, j = idx & 31;
        float v = ls[0][f16i][j] + ls[1][f16i][j] + ls[2][f16i][j] + ls[3][f16i][j];
        int stat = j >> 3, e = j & 7;
        atomicAdd(&sums[stat * 128 + f16i * 8 + e], v);
    }
}

// ---- standalone BN stats (fallback path) ----
__global__ __launch_bounds__(256) void k_stats(const float* __restrict__ accL,
                                               const float* __restrict__ accH, int N,
                                               float* __restrict__ sums) {
    int tid = threadIdx.x;
    int l5 = tid & 31;
    int g = tid >> 5;
    float4 l1 = {0, 0, 0, 0}, l2 = {0, 0, 0, 0}, h1 = {0, 0, 0, 0}, h2 = {0, 0, 0, 0};
    for (int r = blockIdx.x * 8 + g; r < N; r += gridDim.x * 8) {
        float4 v = *(const float4*)&accL[(long)r * HIDF + l5 * 4];
        l1.x += v.x; l1.y += v.y; l1.z += v.z; l1.w += v.w;
        l2.x += v.x * v.x; l2.y += v.y * v.y; l2.z += v.z * v.z; l2.w += v.w * v.w;
        float4 u = *(const float4*)&accH[(long)r * HIDF + l5 * 4];
        h1.x += u.x; h1.y += u.y; h1.z += u.z; h1.w += u.w;
        h2.x += u.x * u.x; h2.y += u.y * u.y; h2.z += u.z * u.z; h2.w += u.w * u.w;
    }
    __shared__ float4 s1[256], s2[256], s3[256], s4[256];
    s1[tid] = l1; s2[tid] = l2; s3[tid] = h1; s4[tid] = h2;
    __syncthreads();
    if (tid < 32) {
        float4 a = s1[tid], bq = s2[tid], c = s3[tid], d = s4[tid];
        for (int gg = 1; gg < 8; ++gg) {
            float4 t;
            t = s1[gg * 32 + tid]; a.x += t.x; a.y += t.y; a.z += t.z; a.w += t.w;
            t = s2[gg * 32 + tid]; bq.x += t.x; bq.y += t.y; bq.z += t.z; bq.w += t.w;
            t = s3[gg * 32 + tid]; c.x += t.x; c.y += t.y; c.z += t.z; c.w += t.w;
            t = s4[gg * 32 + tid]; d.x += t.x; d.y += t.y; d.z += t.z; d.w += t.w;
        }
        int f = tid * 4;
        atomicAdd(&sums[f + 0], a.x); atomicAdd(&sums[f + 1], a.y);
        atomicAdd(&sums[f + 2], a.z); atomicAdd(&sums[f + 3], a.w);
        atomicAdd(&sums[128 + f + 0], bq.x); atomicAdd(&sums[128 + f + 1], bq.y);
        atomicAdd(&sums[128 + f + 2], bq.z); atomicAdd(&sums[128 + f + 3], bq.w);
        atomicAdd(&sums[256 + f + 0], c.x); atomicAdd(&sums[256 + f + 1], c.y);
        atomicAdd(&sums[256 + f + 2], c.z); atomicAdd(&sums[256 + f + 3], c.w);
        atomicAdd(&sums[384 + f + 0], d.x); atomicAdd(&sums[384 + f + 1], d.y);
        atomicAdd(&sums[384 + f + 2], d.z); atomicAdd(&sums[384 + f + 3], d.w);
    }
}

// ---- finalize BN affine for both encoders + aaW = a_add @ W_up ----
__global__ void k_bnfin(const float* __restrict__ sums, int N, const float* __restrict__ scale,
                        const float* __restrict__ shift, const float* __restrict__ Wup,
                        float* __restrict__ a_mul, float* __restrict__ a_add,
                        float* __restrict__ aaW) {
    __shared__ float sh_add[2][128];
    int f = threadIdx.x;
    for (int enc = 0; enc < 2; ++enc) {
        float mu = sums[enc * 256 + f] / (float)N;
        float var = sums[enc * 256 + 128 + f] / (float)N - mu * mu;
        float rstd = rsqrtf(var + 1e-5f);
        float am = rstd * scale[f];
        a_mul[enc * 128 + f] = am;
        float ad = shift[f] - mu * am;
        a_add[enc * 128 + f] = ad;
        sh_add[enc][f] = ad;
    }
    __syncthreads();
    int n = f;
    float s0 = 0.f, s1 = 0.f;
    for (int ff = 0; ff < 128; ++ff) {
        float w = Wup[ff * 128 + n];
        s0 += sh_add[0][ff] * w;
        s1 += sh_add[1][ff] * w;
    }
    aaW[n] = s0;
    aaW[128 + n] = s1;
}

extern "C" void kernel_launch(void* const* d_in, const int* in_sizes, int n_in, void* d_out,
                              int out_size, void* d_ws, size_t ws_size, hipStream_t stream) {
    const float* x = (const float*)d_in[0];
    const int* edge_index = (const int*)d_in[1];
    const float* W_in = (const float*)d_in[2];
    const float* b_in = (const float*)d_in[3];
    const float* gamma_L = (const float*)d_in[4];
    const float* gamma_H = (const float*)d_in[5];
    const float* bn_scale = (const float*)d_in[6];
    const float* bn_shift = (const float*)d_in[7];
    const float* W_up = (const float*)d_in[8];
    const float* b_up = (const float*)d_in[9];
    float* out = (float*)d_out;

    const int HID = in_sizes[3];       // 128
    const int IN = in_sizes[2] / HID;  // 500
    const int N = in_sizes[0] / IN;    // 50000
    const int E = in_sizes[1] / 2;     // 800000
    const int K = in_sizes[4] - 1;     // 10

    const int* src = edge_index;
    const int* dst = edge_index + E;

    const int KP = (IN + 31) & ~31;    // 500 -> 512

    char* base = (char*)d_ws;
    size_t off = 0;
    auto take = [&](size_t bytes) -> char* {
        char* r = base + off;
        off += alup(bytes);
        return r;
    };
    int* deg = (int*)take((size_t)N * 4);
    int* row_ptr = (int*)take((size_t)(N + 1) * 4);
    int* fill = (int*)take((size_t)N * 4);
    float* dinv = (float*)take((size_t)N * 4);
    int* bsum = (int*)take(1024 * 4);
    int* csr_src = (int*)take((size_t)E * 4);
    float* csr_w = (float*)take((size_t)E * 4);
    float* accL = (float*)take((size_t)N * HID * 4);
    float* accH = (float*)take((size_t)N * HID * 4);
    float* sums = (float*)take(512 * 4);
    float* cL = (float*)take(64 * 4);
    float* cH = (float*)take(64 * 4);
    float* a_mul = (float*)take(256 * 4);
    float* a_add = (float*)take(256 * 4);
    float* aaW = (float*)take(256 * 4);
    _Float16* Wt_h = (_Float16*)take((size_t)HID * KP * 2);
    _Float16* Wt_l = (_Float16*)take((size_t)HID * KP * 2);
    _Float16* Wup_h = (_Float16*)take((size_t)HID * HID * 2);
    _Float16* Wup_l = (_Float16*)take((size_t)HID * HID * 2);

    size_t per16 = alup((size_t)N * HID * 2);
    long stride16 = (long)(per16 / 2);
    __half* tb16 = (__half*)(base + off);
    bool deferred = (off + (size_t)(K + 1) * per16) <= ws_size && K < 60;
    size_t per32 = alup((size_t)N * HID * 4);
    long stride32 = (long)(per32 / 4);
    float* fb = (float*)(base + off);
    if (!deferred && off + 2 * per32 > ws_size) deferred = true;

    hipMemsetAsync(deg, 0, (size_t)N * 4, stream);
    hipMemsetAsync(fill, 0, (size_t)N * 4, stream);
    hipMemsetAsync(sums, 0, 512 * 4, stream);

    k_coef<<<1, 64, 0, stream>>>(gamma_L, gamma_H, K, cL, cH);
    k_deg<<<cdiv(E, 256), 256, 0, stream>>>(dst, E, deg);

    // multi-block scan (dinv fused into phase 1)
    int nb = cdiv(N + 1, 256);
    if (nb <= 1024) {
        k_scan1<<<nb, 256, 0, stream>>>(deg, N, bsum, dinv);
        k_scan2<<<1, 1024, 0, stream>>>(bsum, nb);
        k_scan3<<<nb, 256, 0, stream>>>(deg, bsum, N, row_ptr);
    } else {
        k_scan<<<1, 1024, 0, stream>>>(deg, N, row_ptr, dinv);
    }

    k_scatter<<<cdiv(E, 256), 256, 0, stream>>>(src, dst, E, row_ptr, fill, dinv, csr_src,
                                                csr_w);
    k_wprep<<<cdiv(HID * HID, 512), 512, 0, stream>>>(W_up, HID, HID, Wup_h, Wup_l);

    if (deferred) {
        k_wprep<<<cdiv(HID * KP, 512), 512, 0, stream>>>(W_in, IN, KP, Wt_h, Wt_l);
        k_gemm_in_mfma<<<cdiv(N, 128), 512, 0, stream>>>(x, Wt_h, Wt_l, b_in, tb16, N, IN, KP);
        for (int j = 1; j <= K; ++j) {
            const __half* tin = tb16 + (long)(j - 1) * stride16;
            __half* tout = tb16 + (long)j * stride16;
            k_prop_h<<<cdiv(N, 4), 256, 0, stream>>>(row_ptr, csr_src, csr_w, tin, tout, N);
        }
        k_combine_h2<<<512, 256, 0, stream>>>(tb16, stride16, K, accL, accH, cL, cH, N, sums);
    } else {
        float* h = fb;
        float* ta = fb + stride32;
        k_gemm_in_f<<<cdiv(N, 128), 512, 0, stream>>>(x, W_in, b_in, h, accL, accH, cL, cH,
                                                      N, IN);
        const float* tin = h;
        float* tout = ta;
        for (int j = 1; j <= K; ++j) {
            int write_t = (j < K) ? 1 : 0;
            k_prop<<<cdiv(N, 4), 256, 0, stream>>>(row_ptr, csr_src, csr_w, tin, tout, accL,
                                                   accH, cL, cH, j, N, write_t);
            const float* nt = tout;
            tout = (nt == ta) ? h : ta;
            tin = nt;
        }
        k_stats<<<200, 256, 0, stream>>>(accL, accH, N, sums);
    }

    k_bnfin<<<1, 128, 0, stream>>>(sums, N, bn_scale, bn_shift, W_up, a_mul, a_add, aaW);
    dim3 gup(cdiv(N, 128), 2);
    k_gemm_up_mfma<<<gup, 512, 0, stream>>>(accL, accH, Wup_h, Wup_l, b_up, a_mul, aaW, out,
                                            N);
}